// Round 1
// 250.005 us; speedup vs baseline: 1.0736x; 1.0736x over previous
//
#include <hip/hip_runtime.h>
#include <hip/hip_bf16.h>

#define CDIV(a,b) (((a)+(b)-1)/(b))
#define NBUCK_MAX 512   // buckets of 128 nodes; supports N up to 65536 (ebuf packing needs N<=65536)

typedef __attribute__((ext_vector_type(8))) short short8;
typedef __attribute__((ext_vector_type(4))) float f32x4;
typedef __attribute__((ext_vector_type(2))) float f32x2;

static __device__ __forceinline__ unsigned short f2bf(float f){
  union { float f; unsigned u; } v; v.f = f;
  unsigned r = v.u + 0x7fffu + ((v.u >> 16) & 1u);   // RNE
  return (unsigned short)(r >> 16);
}
static __device__ __forceinline__ unsigned pack2(float lo, float hi){
  return (unsigned)f2bf(lo) | ((unsigned)f2bf(hi) << 16);
}
static __device__ __forceinline__ float bf2f(unsigned short s){
  union { unsigned u; float f; } v; v.u = ((unsigned)s) << 16; return v.f;
}
// pack 4 f32 -> 4 fp8 e4m3 bytes (byte0=a .. byte3=d)
static __device__ __forceinline__ unsigned pk_fp8x4(float a, float b, float c, float d){
  int v = __builtin_amdgcn_cvt_pk_fp8_f32(a, b, 0, false);
  v = __builtin_amdgcn_cvt_pk_fp8_f32(c, d, v, true);
  return (unsigned)v;
}

// accumulate 8 fp8 bytes (uint2) into a0..a7
#define ACCQ8(v) { f32x2 p0 = __builtin_amdgcn_cvt_pk_f32_fp8((int)v.x, false); \
                   f32x2 p1 = __builtin_amdgcn_cvt_pk_f32_fp8((int)v.x, true);  \
                   f32x2 p2 = __builtin_amdgcn_cvt_pk_f32_fp8((int)v.y, false); \
                   f32x2 p3 = __builtin_amdgcn_cvt_pk_f32_fp8((int)v.y, true);  \
                   a0 += p0.x; a1 += p0.y; a2 += p1.x; a3 += p1.y; \
                   a4 += p2.x; a5 += p2.y; a6 += p3.x; a7 += p3.y; }

// ---------------- weight pack args ----------------
// perm: first-128 K positions hold channel pi(k) = (k&7)*16 + (k>>3) (matches fp8 gather row layout)

struct WtpArgs {
  const float *W0, *W1, *bl, *g, *b, *rm, *rv;
  unsigned short* Bpk; float *sc; float *sh;
  int kblk, dout, do_bn, nblk, perm;
};

static __device__ __forceinline__ void wtp_one(const WtpArgs& a, int idx){
  int NB16 = a.kblk*32*a.dout;
  if (idx < NB16){
    int j = idx & 7, lane = (idx >> 3) & 63, rest = idx >> 9;
    int NT = a.dout >> 4;
    int nt = rest % NT, kk = rest / NT;
    int nn = nt*16 + (lane & 15);
    int k  = kk*32 + ((lane >> 4) * 8) + j;
    float v;
    if (k < 128){
      int kc = a.perm ? (((k & 7) << 4) | (k >> 3)) : k;
      v = a.W0[nn*128 + kc];
    } else {
      v = a.W1[nn*128 + (k - 128)];
    }
    a.Bpk[idx] = f2bf(v);
  } else if (a.do_bn && idx < NB16 + a.dout){
    int jj = idx - NB16;
    float s = a.g[jj] * rsqrtf(a.rv[jj] + 1e-5f);
    a.sc[jj] = s;
    a.sh[jj] = (a.bl[jj] - a.rm[jj]) * s + a.b[jj];
  }
}

// ---------------- prep: cast x->bf16 | x->fp8(perm) | bucket histogram | weight pack, one launch ----------------

__global__ __launch_bounds__(256) void k_prep(const float* __restrict__ x, int n2, unsigned* __restrict__ xb,
                                              unsigned* __restrict__ xq,
                                              const int* __restrict__ dst, int E,
                                              int* __restrict__ bcnt, int nbuck,
                                              int castBlocks, int xqBlocks, int histBlocks,
                                              WtpArgs a0, WtpArgs a1, WtpArgs a2, WtpArgs a3){
  __shared__ int s[NBUCK_MAX];
  int b = blockIdx.x, t = threadIdx.x;
  if (b < castBlocks){
    int i = b*256 + t;
    if (i < n2){
      float2 v = ((const float2*)x)[i];
      xb[i] = pack2(v.x, v.y);
    }
    return;
  }
  b -= castBlocks;
  if (b < xqBlocks){
    // fp8 permuted copy of x: thread (row,c) packs channels {j*16+c} into bytes row*128 + c*8 + j
    int i = b*256 + t;               // i in [0, N*16)
    if (i < (n2 >> 2)){
      int row = i >> 4, c = i & 15;
      const float* xr = x + (size_t)row*128 + c;
      float v0 = xr[0],  v1 = xr[16], v2 = xr[32],  v3 = xr[48];
      float v4 = xr[64], v5 = xr[80], v6 = xr[96],  v7 = xr[112];
      uint2 q;
      q.x = pk_fp8x4(v0, v1, v2, v3);
      q.y = pk_fp8x4(v4, v5, v6, v7);
      ((uint2*)xq)[i] = q;
    }
    return;
  }
  b -= xqBlocks;
  if (b < histBlocks){
    for (int i=t;i<nbuck;i+=256) s[i] = 0;
    __syncthreads();
    constexpr int EPT = 16;
    int e0 = b*256*EPT;
    #pragma unroll
    for (int i=0;i<EPT;i++){
      int e = e0 + i*256 + t;
      if (e < E) atomicAdd(&s[dst[e] >> 7], 1);
    }
    __syncthreads();
    for (int i=t;i<nbuck;i+=256){
      int c = s[i];
      if (c > 0) atomicAdd(&bcnt[i], c);
    }
    return;
  }
  b -= histBlocks;
  if (b < a0.nblk){ wtp_one(a0, b*256 + t); return; }
  b -= a0.nblk;
  if (b < a1.nblk){ wtp_one(a1, b*256 + t); return; }
  b -= a1.nblk;
  if (b < a2.nblk){ wtp_one(a2, b*256 + t); return; }
  b -= a2.nblk;
  wtp_one(a3, b*256 + t);
}

// single block: exclusive scan of bcnt[0..nbuck) -> bbase[0..nbuck], bbase[nbuck]=E
__global__ __launch_bounds__(256) void k_bscan(const int* __restrict__ bcnt, int nbuck,
                                               int* __restrict__ bbase){
  __shared__ int s[256];
  int t = threadIdx.x;
  int a0 = (2*t   < nbuck) ? bcnt[2*t]   : 0;
  int a1 = (2*t+1 < nbuck) ? bcnt[2*t+1] : 0;
  s[t] = a0 + a1; __syncthreads();
  for (int d=1; d<256; d<<=1){
    int u = (t>=d) ? s[t-d] : 0;
    __syncthreads();
    s[t] += u;
    __syncthreads();
  }
  int excl = s[t] - (a0 + a1);
  if (2*t   < nbuck) bbase[2*t]   = excl;
  if (2*t+1 < nbuck) bbase[2*t+1] = excl + a0;
  if (t == 255) bbase[nbuck] = s[255];
}

// Pass A: bin edges into 128-node buckets; bucket region in ebuf == final csr region.
// Packed entry: (local_dst << 16) | src  (requires N <= 65536)
__global__ __launch_bounds__(256) void k_bucketA(const int* __restrict__ src, const int* __restrict__ dst,
                                                 int E, const int* __restrict__ bbase,
                                                 int* __restrict__ bcur, unsigned* __restrict__ ebuf, int nbuck){
  __shared__ int scnt[NBUCK_MAX];
  __shared__ int sbase[NBUCK_MAX];
  __shared__ int sboff[NBUCK_MAX];
  int t = threadIdx.x;
  for (int i=t;i<nbuck;i+=256) scnt[i] = 0;
  __syncthreads();
  constexpr int EPT = 16;
  int e0 = blockIdx.x*256*EPT;
  int b[EPT]; unsigned pk[EPT];
  #pragma unroll
  for (int i=0;i<EPT;i++){
    int e = e0 + i*256 + t;
    if (e < E){
      int d = dst[e];
      b[i] = d >> 7;
      pk[i] = ((unsigned)(d & 127) << 16) | (unsigned)src[e];
      atomicAdd(&scnt[b[i]], 1);
    } else b[i] = -1;
  }
  __syncthreads();
  for (int i=t;i<nbuck;i+=256){
    int c = scnt[i];
    sbase[i] = (c > 0) ? atomicAdd(&bcur[i], c) : 0;
    sboff[i] = bbase[i];
    scnt[i] = 0;
  }
  __syncthreads();
  #pragma unroll
  for (int i=0;i<EPT;i++){
    if (b[i] >= 0){
      int p = atomicAdd(&scnt[b[i]], 1);
      ebuf[(size_t)sboff[b[i]] + sbase[b[i]] + p] = pk[i];
    }
  }
}

// Pass B: one block per bucket; local degree count + scan -> off + csr scatter in ~8KB window.
__global__ __launch_bounds__(256) void k_bucketB(const unsigned* __restrict__ ebuf, const int* __restrict__ bbase,
                                                 int N, int* __restrict__ off, int* __restrict__ csr){
  int b = blockIdx.x;
  int n0 = b << 7, n1 = min(n0 + 128, N);
  __shared__ int sdeg[128];
  __shared__ int sabs[129];
  __shared__ int cur[128];
  int t = threadIdx.x;
  if (t < 128){ sdeg[t] = 0; cur[t] = 0; }
  __syncthreads();
  int e0 = bbase[b], e1 = bbase[b+1];
  for (int e = e0 + t; e < e1; e += 256)
    atomicAdd(&sdeg[ebuf[e] >> 16], 1);
  __syncthreads();
  for (int d=1; d<128; d<<=1){
    int u = (t < 128 && t >= d) ? sdeg[t-d] : 0;
    __syncthreads();
    if (t < 128) sdeg[t] += u;
    __syncthreads();
  }
  if (t == 0) sabs[0] = e0;
  if (t < 128) sabs[t+1] = e0 + sdeg[t];
  __syncthreads();
  if (t <= n1 - n0) off[n0 + t] = sabs[t];
  for (int e = e0 + t; e < e1; e += 256){
    unsigned pr = ebuf[e];
    int ln = (int)(pr >> 16);
    int p = atomicAdd(&cur[ln], 1);
    csr[sabs[ln] + p] = (int)(pr & 0xffffu);
  }
}

// ---------------- mean aggregation, 128-dim fp8 rows: 4 nodes/wave, 16 lanes x uint2, 8-deep unroll ----------------
// input rows are fp8(perm); output mean rows are bf16 at the SAME permuted positions (B-pack compensates).

__global__ __launch_bounds__(256) void k_agg(const uint2* __restrict__ hq, const int* __restrict__ off,
                                             const int* __restrict__ csr, int n, uint4* __restrict__ mean4){
  int tid = blockIdx.x*256 + threadIdx.x;
  int lane = threadIdx.x & 63;
  int sl = lane & 15;
  int node = (tid >> 6)*4 + (lane >> 4);
  bool valid = node < n;
  int s0 = valid ? off[node]   : 0;
  int s1 = valid ? off[node+1] : 0;
  float a0=0,a1=0,a2=0,a3=0,a4=0,a5=0,a6=0,a7=0;
  int e = s0;
  for (; e + 8 <= s1; e += 8){
    int i0 = csr[e],   i1 = csr[e+1], i2 = csr[e+2], i3 = csr[e+3];
    int i4 = csr[e+4], i5 = csr[e+5], i6 = csr[e+6], i7 = csr[e+7];
    uint2 v0 = hq[(size_t)i0*16 + sl];
    uint2 v1 = hq[(size_t)i1*16 + sl];
    uint2 v2 = hq[(size_t)i2*16 + sl];
    uint2 v3 = hq[(size_t)i3*16 + sl];
    uint2 v4 = hq[(size_t)i4*16 + sl];
    uint2 v5 = hq[(size_t)i5*16 + sl];
    uint2 v6 = hq[(size_t)i6*16 + sl];
    uint2 v7 = hq[(size_t)i7*16 + sl];
    ACCQ8(v0); ACCQ8(v1); ACCQ8(v2); ACCQ8(v3);
    ACCQ8(v4); ACCQ8(v5); ACCQ8(v6); ACCQ8(v7);
  }
  for (; e + 4 <= s1; e += 4){
    int i0 = csr[e], i1 = csr[e+1], i2 = csr[e+2], i3 = csr[e+3];
    uint2 v0 = hq[(size_t)i0*16 + sl];
    uint2 v1 = hq[(size_t)i1*16 + sl];
    uint2 v2 = hq[(size_t)i2*16 + sl];
    uint2 v3 = hq[(size_t)i3*16 + sl];
    ACCQ8(v0); ACCQ8(v1); ACCQ8(v2); ACCQ8(v3);
  }
  for (; e < s1; e++){
    uint2 v = hq[(size_t)csr[e]*16 + sl];
    ACCQ8(v);
  }
  if (valid){
    int d = s1 - s0;
    float inv = 1.0f / (float)(d > 0 ? d : 1);
    uint4 o;
    o.x = pack2(a0*inv, a1*inv);
    o.y = pack2(a2*inv, a3*inv);
    o.z = pack2(a4*inv, a5*inv);
    o.w = pack2(a6*inv, a7*inv);
    mean4[(size_t)node*16 + sl] = o;
  }
}

// ---------------- hidden-layer GEMM (LDS-staged B, round-4 structure), optional fused yl mini-GEMM ----------------
// C[N][128] = [A0|A1]@B (K=256), BN+ReLU, bf16 out (+ fp8(perm) copy when !YL).
// If YL: also yl = C@Wl2^T (K=128, DOUT=64) -> outyl as fp8(perm2).

template<bool YL>
__global__ __launch_bounds__(256, 2) void k_gemm_hid(
    const unsigned short* __restrict__ A0, const unsigned short* __restrict__ A1,
    const unsigned short* __restrict__ Bpk, const float* __restrict__ sc,
    const float* __restrict__ sh, const unsigned short* __restrict__ BpkL,
    unsigned short* __restrict__ outh, unsigned* __restrict__ outq,
    unsigned* __restrict__ outyl, int n){
  __shared__ unsigned short Bs[256*128];   // 64 KB
  int t = threadIdx.x;
  {
    const uint4* s = (const uint4*)Bpk;
    uint4* d = (uint4*)Bs;
    #pragma unroll
    for (int i=0;i<16;i++) d[i*256 + t] = s[i*256 + t];
  }
  __syncthreads();

  int lane = t & 63, w = t >> 6;
  int quad = lane >> 4, c = lane & 15;
  int mb = blockIdx.x*128, woff = w*32;
  int r0 = mb + woff + c;
  int r1 = r0 + 16;

  f32x4 acc[2][8];
  #pragma unroll
  for (int mt=0;mt<2;mt++)
    #pragma unroll
    for (int nt=0;nt<8;nt++) acc[mt][nt] = (f32x4){0.f,0.f,0.f,0.f};

  #pragma unroll
  for (int kk=0; kk<8; kk++){
    const unsigned short* ab = (kk >= 4) ? A1 : A0;
    int ka = (kk & 3)*32 + quad*8;
    short8 a0 = {0,0,0,0,0,0,0,0}, a1 = {0,0,0,0,0,0,0,0};
    if (r0 < n) a0 = *(const short8*)(ab + (size_t)r0*128 + ka);
    if (r1 < n) a1 = *(const short8*)(ab + (size_t)r1*128 + ka);
    #pragma unroll
    for (int nt=0; nt<8; nt++){
      short8 b = *(const short8*)&Bs[(size_t)((kk*8 + nt)*64 + lane)*8];
      acc[0][nt] = __builtin_amdgcn_mfma_f32_16x16x32_bf16(a0, b, acc[0][nt], 0, 0, 0);
      acc[1][nt] = __builtin_amdgcn_mfma_f32_16x16x32_bf16(a1, b, acc[1][nt], 0, 0, 0);
    }
  }

  float scv[8], shv[8];
  #pragma unroll
  for (int nt=0;nt<8;nt++){ scv[nt] = sc[nt*16 + c]; shv[nt] = sh[nt*16 + c]; }

  #pragma unroll
  for (int mt=0; mt<2; mt++){
    #pragma unroll
    for (int r=0;r<4;r++){
      int row = mb + woff + mt*16 + quad*4 + r;
      if (row < n){
        float u[8];
        #pragma unroll
        for (int nt=0;nt<8;nt++){
          float uu = acc[mt][nt][r]*scv[nt] + shv[nt];
          u[nt] = fmaxf(uu, 0.f);
          outh[(size_t)row*128 + nt*16 + c] = f2bf(u[nt]);
        }
        if constexpr (!YL){
          // fp8(perm) copy for the next layer's gather: bytes row*128 + c*8 + j hold channel j*16+c
          uint2 q;
          q.x = pk_fp8x4(u[0], u[1], u[2], u[3]);
          q.y = pk_fp8x4(u[4], u[5], u[6], u[7]);
          ((uint2*)outq)[(size_t)row*16 + c] = q;
        }
      }
    }
  }

  if constexpr (YL){
    __syncthreads();   // everyone done reading Bs; outh tile visible block-wide after barrier
    {
      // restage own h tile (128 rows x 128 bf16 = 2048 uint4) into Bs[0..16384)
      uint4* d = (uint4*)Bs;
      const uint4* s4 = (const uint4*)outh;
      #pragma unroll
      for (int i=0;i<8;i++){
        int idx = i*256 + t;
        int row = idx >> 4;
        int gr = mb + row; if (gr > n-1) gr = n-1;
        d[idx] = s4[(size_t)gr*16 + (idx & 15)];
      }
      // stage BpkL (128x64 = 1024 uint4) at short-offset 16384
      const uint4* sL = (const uint4*)BpkL;
      #pragma unroll
      for (int i=0;i<4;i++) d[2048 + i*256 + t] = sL[i*256 + t];
    }
    __syncthreads();
    f32x4 acc2[2][4];
    #pragma unroll
    for (int mt=0;mt<2;mt++)
      #pragma unroll
      for (int nt=0;nt<4;nt++) acc2[mt][nt] = (f32x4){0.f,0.f,0.f,0.f};
    int r0l = woff + c, r1l = r0l + 16;
    #pragma unroll
    for (int kk=0; kk<4; kk++){
      int ka = kk*32 + quad*8;
      short8 a0 = *(const short8*)&Bs[(size_t)r0l*128 + ka];
      short8 a1 = *(const short8*)&Bs[(size_t)r1l*128 + ka];
      #pragma unroll
      for (int nt=0; nt<4; nt++){
        short8 b = *(const short8*)&Bs[16384 + (size_t)((kk*4 + nt)*64 + lane)*8];
        acc2[0][nt] = __builtin_amdgcn_mfma_f32_16x16x32_bf16(a0, b, acc2[0][nt], 0, 0, 0);
        acc2[1][nt] = __builtin_amdgcn_mfma_f32_16x16x32_bf16(a1, b, acc2[1][nt], 0, 0, 0);
      }
    }
    #pragma unroll
    for (int mt=0; mt<2; mt++){
      #pragma unroll
      for (int r=0;r<4;r++){
        int row = mb + woff + mt*16 + quad*4 + r;
        if (row < n){
          // fp8(perm2): byte row*64 + c*4 + nt holds channel nt*16+c
          unsigned q = pk_fp8x4(acc2[0][0][r], acc2[0][1][r], acc2[0][2][r], acc2[0][3][r]);
          unsigned q1 = pk_fp8x4(acc2[1][0][r], acc2[1][1][r], acc2[1][2][r], acc2[1][3][r]);
          outyl[(size_t)row*16 + c] = (mt == 0) ? q : q1;
        }
      }
    }
  }
}

// ---------------- fused layer-3: mean-yl gather (64-dim fp8) + GEMM (h_b@Wr2^T) + BN + L2norm ----------------

__global__ __launch_bounds__(256, 2) void k_aggf(
    const uint2* __restrict__ ylq, const int* __restrict__ off, const int* __restrict__ csr,
    const unsigned short* __restrict__ A0, const unsigned short* __restrict__ BpkR,
    const float* __restrict__ sc, const float* __restrict__ sh,
    float* __restrict__ outf, int n){
  __shared__ unsigned short Ms[128*64];   // 16 KB mean-yl tile (bf16, perm2 positions)
  __shared__ unsigned short Bs[128*64];   // 16 KB BpkR
  int t = threadIdx.x;
  {
    const uint4* s = (const uint4*)BpkR;
    uint4* d = (uint4*)Bs;
    #pragma unroll
    for (int i=0;i<4;i++) d[i*256 + t] = s[i*256 + t];
  }
  int lane = t & 63, w = t >> 6;
  int mb = blockIdx.x*128;
  int sl8 = lane & 7;

  // gather phase: wave w covers local rows [w*32, w*32+32), 8 nodes at a time
  #pragma unroll
  for (int it=0; it<4; it++){
    int ln = w*32 + it*8 + (lane >> 3);
    int node = mb + ln;
    bool valid = node < n;
    int s0 = valid ? off[node]   : 0;
    int s1 = valid ? off[node+1] : 0;
    float a0=0,a1=0,a2=0,a3=0,a4=0,a5=0,a6=0,a7=0;
    int e = s0;
    for (; e + 4 <= s1; e += 4){
      int i0 = csr[e], i1 = csr[e+1], i2 = csr[e+2], i3 = csr[e+3];
      uint2 v0 = ylq[(size_t)i0*8 + sl8];
      uint2 v1 = ylq[(size_t)i1*8 + sl8];
      uint2 v2 = ylq[(size_t)i2*8 + sl8];
      uint2 v3 = ylq[(size_t)i3*8 + sl8];
      ACCQ8(v0); ACCQ8(v1); ACCQ8(v2); ACCQ8(v3);
    }
    for (; e < s1; e++){
      uint2 v = ylq[(size_t)csr[e]*8 + sl8];
      ACCQ8(v);
    }
    int d = s1 - s0;
    float inv = 1.0f / (float)(d > 0 ? d : 1);
    uint4 o;
    o.x = pack2(a0*inv, a1*inv);
    o.y = pack2(a2*inv, a3*inv);
    o.z = pack2(a4*inv, a5*inv);
    o.w = pack2(a6*inv, a7*inv);
    ((uint4*)Ms)[ln*8 + sl8] = o;
  }
  __syncthreads();

  // GEMM phase: C = h_b @ Wr2^T (K=128), + mean-yl, BN, L2-normalize
  int quad = lane >> 4, c = lane & 15;
  int woff = w*32;
  int r0 = mb + woff + c;
  int r1 = r0 + 16;
  f32x4 acc[2][4];
  #pragma unroll
  for (int mt=0;mt<2;mt++)
    #pragma unroll
    for (int nt=0;nt<4;nt++) acc[mt][nt] = (f32x4){0.f,0.f,0.f,0.f};
  #pragma unroll
  for (int kk=0; kk<4; kk++){
    int ka = kk*32 + quad*8;
    short8 a0 = {0,0,0,0,0,0,0,0}, a1 = {0,0,0,0,0,0,0,0};
    if (r0 < n) a0 = *(const short8*)(A0 + (size_t)r0*128 + ka);
    if (r1 < n) a1 = *(const short8*)(A0 + (size_t)r1*128 + ka);
    #pragma unroll
    for (int nt=0; nt<4; nt++){
      short8 b = *(const short8*)&Bs[(size_t)((kk*4 + nt)*64 + lane)*8];
      acc[0][nt] = __builtin_amdgcn_mfma_f32_16x16x32_bf16(a0, b, acc[0][nt], 0, 0, 0);
      acc[1][nt] = __builtin_amdgcn_mfma_f32_16x16x32_bf16(a1, b, acc[1][nt], 0, 0, 0);
    }
  }

  float scv[4], shv[4];
  #pragma unroll
  for (int nt=0;nt<4;nt++){ scv[nt] = sc[nt*16 + c]; shv[nt] = sh[nt*16 + c]; }

  #pragma unroll
  for (int mt=0; mt<2; mt++){
    #pragma unroll
    for (int r=0;r<4;r++){
      int lr = woff + mt*16 + quad*4 + r;
      int row = mb + lr;
      float v[4];
      float ss = 0.f;
      if (row < n){
        #pragma unroll
        for (int nt=0;nt<4;nt++){
          // Ms holds perm2 positions: channel nt*16+c lives at position c*4+nt
          float u = acc[mt][nt][r] + bf2f(Ms[lr*64 + c*4 + nt]);
          u = u*scv[nt] + shv[nt];
          v[nt] = u;
          ss += u*u;
        }
      } else {
        #pragma unroll
        for (int nt=0;nt<4;nt++) v[nt] = 0.f;
      }
      ss += __shfl_xor(ss, 1, 64);
      ss += __shfl_xor(ss, 2, 64);
      ss += __shfl_xor(ss, 4, 64);
      ss += __shfl_xor(ss, 8, 64);
      float rn = 1.0f / fmaxf(sqrtf(ss), 1e-12f);
      if (row < n){
        #pragma unroll
        for (int nt=0;nt<4;nt++) outf[(size_t)row*64 + nt*16 + c] = v[nt]*rn;
      }
    }
  }
}

// ---------------- launcher ----------------

extern "C" void kernel_launch(void* const* d_in, const int* in_sizes, int n_in,
                              void* d_out, int out_size, void* d_ws, size_t ws_size,
                              hipStream_t stream){
  const float* x = (const float*)d_in[0];
  const int* ei  = (const int*)d_in[1];
  int N = in_sizes[0] / 128;
  int E = in_sizes[1] / 2;
  const int* esrc = ei;
  const int* edst = ei + E;
  int nbuck = CDIV(N, 128);

  const float *Wl[3], *bl[3], *Wr[3], *g[3], *bb[3], *rm[3], *rv[3];
  int dout[3];
  for (int i=0;i<3;i++){
    int base = 2 + 7*i;
    Wl[i]=(const float*)d_in[base];   bl[i]=(const float*)d_in[base+1];
    Wr[i]=(const float*)d_in[base+2]; g[i] =(const float*)d_in[base+3];
    bb[i]=(const float*)d_in[base+4]; rm[i]=(const float*)d_in[base+5];
    rv[i]=(const float*)d_in[base+6];
    dout[i] = in_sizes[base] / 128;
  }

  char* p = (char*)d_ws;
  size_t o = 0;
  auto alloc = [&](size_t bytes)->void*{ void* r = p + o; o += (bytes + 255) & ~(size_t)255; return r; };
  int* bz    = (int*)alloc((size_t)2*nbuck*4);   // bcnt | bcur (one memset)
  int* bcnt  = bz;
  int* bcur  = bz + nbuck;
  int* bbase = (int*)alloc((size_t)(nbuck+1)*4);
  int* off   = (int*)alloc((size_t)(N+1)*4);
  int* csr   = (int*)alloc((size_t)E*4);
  unsigned* ebuf = (unsigned*)alloc((size_t)E*4);
  unsigned* xb   = (unsigned*)alloc((size_t)N*64*4);   // bf16 x (natural)
  unsigned* xq   = (unsigned*)alloc((size_t)N*128);    // fp8 x (perm)
  unsigned* mb   = (unsigned*)alloc((size_t)N*64*4);   // bf16 mean (perm positions)
  unsigned* h_a  = (unsigned*)alloc((size_t)N*64*4);   // bf16 h1 (natural)
  unsigned* haq  = (unsigned*)alloc((size_t)N*128);    // fp8 h1 (perm)
  unsigned* h_b  = (unsigned*)alloc((size_t)N*64*4);   // bf16 h2 (natural)
  unsigned* ylb  = (unsigned*)alloc((size_t)N*64);     // fp8 yl (perm2)
  unsigned short* Bpk01[2];
  float* sc[3]; float* sh[3];
  for (int i=0;i<2;i++) Bpk01[i] = (unsigned short*)alloc((size_t)256*dout[i]*2);
  unsigned short* BpkL = (unsigned short*)alloc((size_t)128*dout[2]*2);
  unsigned short* BpkR = (unsigned short*)alloc((size_t)128*dout[2]*2);
  for (int i=0;i<3;i++){
    sc[i] = (float*)alloc((size_t)dout[i]*4);
    sh[i] = (float*)alloc((size_t)dout[i]*4);
  }

  hipMemsetAsync(bz, 0, (size_t)2*nbuck*4, stream);

  WtpArgs wa[4];
  wa[0] = { Wl[0], Wr[0], bl[0], g[0], bb[0], rm[0], rv[0], Bpk01[0], sc[0], sh[0], 8, dout[0], 1, CDIV(256*dout[0]+dout[0],256), 1 };
  wa[1] = { Wl[1], Wr[1], bl[1], g[1], bb[1], rm[1], rv[1], Bpk01[1], sc[1], sh[1], 8, dout[1], 1, CDIV(256*dout[1]+dout[1],256), 1 };
  wa[2] = { Wl[2], nullptr, nullptr, nullptr, nullptr, nullptr, nullptr, BpkL, nullptr, nullptr, 4, dout[2], 0, CDIV(128*dout[2],256), 0 };
  wa[3] = { Wr[2], nullptr, bl[2], g[2], bb[2], rm[2], rv[2], BpkR, sc[2], sh[2], 4, dout[2], 1, CDIV(128*dout[2]+dout[2],256), 0 };

  int castBlocks = CDIV(N*64, 256);
  int xqBlocks   = CDIV(N*16, 256);
  int histBlocks = CDIV(E, 256*16);
  int prepBlocks = castBlocks + xqBlocks + histBlocks + wa[0].nblk + wa[1].nblk + wa[2].nblk + wa[3].nblk;
  k_prep   <<<prepBlocks,256,0,stream>>>(x, N*64, xb, xq, edst, E, bcnt, nbuck, castBlocks, xqBlocks, histBlocks,
                                         wa[0], wa[1], wa[2], wa[3]);
  k_bscan  <<<1,256,0,stream>>>(bcnt, nbuck, bbase);
  k_bucketA<<<CDIV(E,256*16),256,0,stream>>>(esrc, edst, E, bbase, bcur, ebuf, nbuck);
  k_bucketB<<<nbuck,256,0,stream>>>(ebuf, bbase, N, off, csr);

  // layer 0
  k_agg<<<CDIV(N*16,256),256,0,stream>>>((const uint2*)xq, off, csr, N, (uint4*)mb);
  k_gemm_hid<false><<<CDIV(N,128),256,0,stream>>>((const unsigned short*)mb, (const unsigned short*)xb,
                                                  Bpk01[0], sc[0], sh[0], nullptr,
                                                  (unsigned short*)h_a, haq, nullptr, N);
  // layer 1 (+ fused yl = h_b @ Wl2^T, emitted as fp8 perm2)
  k_agg<<<CDIV(N*16,256),256,0,stream>>>((const uint2*)haq, off, csr, N, (uint4*)mb);
  k_gemm_hid<true><<<CDIV(N,128),256,0,stream>>>((const unsigned short*)mb, (const unsigned short*)h_a,
                                                 Bpk01[1], sc[1], sh[1], BpkL,
                                                 (unsigned short*)h_b, nullptr, ylb, N);
  // layer 2: fused mean-yl gather + final GEMM + BN + L2norm
  k_aggf<<<CDIV(N,128),256,0,stream>>>((const uint2*)ylb, off, csr,
                                       (const unsigned short*)h_b, BpkR, sc[2], sh[2],
                                       (float*)d_out, N);
}

// Round 2
// 240.158 us; speedup vs baseline: 1.1176x; 1.0410x over previous
//
#include <hip/hip_runtime.h>
#include <hip/hip_bf16.h>

#define CDIV(a,b) (((a)+(b)-1)/(b))
#define NBUCK_MAX 512   // buckets of 128 nodes; supports N up to 65536 (ebuf packing needs N<=65536)
#define AGG_CAP  1536   // staged csr entries per k_agg block (32 nodes, mean 512, ~45 sigma headroom)
#define AGGF_CAP 3072   // staged csr entries per k_aggf block (128 nodes, mean 2048, ~22 sigma)

typedef __attribute__((ext_vector_type(8))) short short8;
typedef __attribute__((ext_vector_type(4))) float f32x4;
typedef __attribute__((ext_vector_type(2))) float f32x2;

static __device__ __forceinline__ unsigned short f2bf(float f){
  union { float f; unsigned u; } v; v.f = f;
  unsigned r = v.u + 0x7fffu + ((v.u >> 16) & 1u);   // RNE
  return (unsigned short)(r >> 16);
}
static __device__ __forceinline__ unsigned pack2(float lo, float hi){
  return (unsigned)f2bf(lo) | ((unsigned)f2bf(hi) << 16);
}
static __device__ __forceinline__ float bf2f(unsigned short s){
  union { unsigned u; float f; } v; v.u = ((unsigned)s) << 16; return v.f;
}
// pack 4 f32 -> 4 fp8 e4m3 bytes (byte0=a .. byte3=d)
static __device__ __forceinline__ unsigned pk_fp8x4(float a, float b, float c, float d){
  int v = __builtin_amdgcn_cvt_pk_fp8_f32(a, b, 0, false);
  v = __builtin_amdgcn_cvt_pk_fp8_f32(c, d, v, true);
  return (unsigned)v;
}

// accumulate 16 fp8 bytes (uint4) into a0..a15
#define ACCQ16(v) { f32x2 q0 = __builtin_amdgcn_cvt_pk_f32_fp8((int)v.x, false); \
                    f32x2 q1 = __builtin_amdgcn_cvt_pk_f32_fp8((int)v.x, true);  \
                    f32x2 q2 = __builtin_amdgcn_cvt_pk_f32_fp8((int)v.y, false); \
                    f32x2 q3 = __builtin_amdgcn_cvt_pk_f32_fp8((int)v.y, true);  \
                    f32x2 q4 = __builtin_amdgcn_cvt_pk_f32_fp8((int)v.z, false); \
                    f32x2 q5 = __builtin_amdgcn_cvt_pk_f32_fp8((int)v.z, true);  \
                    f32x2 q6 = __builtin_amdgcn_cvt_pk_f32_fp8((int)v.w, false); \
                    f32x2 q7 = __builtin_amdgcn_cvt_pk_f32_fp8((int)v.w, true);  \
                    a0 += q0.x; a1 += q0.y; a2  += q1.x; a3  += q1.y; \
                    a4 += q2.x; a5 += q2.y; a6  += q3.x; a7  += q3.y; \
                    a8 += q4.x; a9 += q4.y; a10 += q5.x; a11 += q5.y; \
                    a12 += q6.x; a13 += q6.y; a14 += q7.x; a15 += q7.y; }

// ---------------- weight pack args ----------------
// perm: first-128 K positions hold channel pi(k) = (k&7)*16 + (k>>3) (matches gemm-epilogue fp8 row layout)

struct WtpArgs {
  const float *W0, *W1, *bl, *g, *b, *rm, *rv;
  unsigned short* Bpk; float *sc; float *sh;
  int kblk, dout, do_bn, nblk, perm;
};

static __device__ __forceinline__ void wtp_one(const WtpArgs& a, int idx){
  int NB16 = a.kblk*32*a.dout;
  if (idx < NB16){
    int j = idx & 7, lane = (idx >> 3) & 63, rest = idx >> 9;
    int NT = a.dout >> 4;
    int nt = rest % NT, kk = rest / NT;
    int nn = nt*16 + (lane & 15);
    int k  = kk*32 + ((lane >> 4) * 8) + j;
    float v;
    if (k < 128){
      int kc = a.perm ? (((k & 7) << 4) | (k >> 3)) : k;
      v = a.W0[nn*128 + kc];
    } else {
      v = a.W1[nn*128 + (k - 128)];
    }
    a.Bpk[idx] = f2bf(v);
  } else if (a.do_bn && idx < NB16 + a.dout){
    int jj = idx - NB16;
    float s = a.g[jj] * rsqrtf(a.rv[jj] + 1e-5f);
    a.sc[jj] = s;
    a.sh[jj] = (a.bl[jj] - a.rm[jj]) * s + a.b[jj];
  }
}

// ---------------- prep: cast x->bf16 + x->fp8(identity) in one pass | bucket histogram | weight pack ----------------

__global__ __launch_bounds__(256) void k_prep(const float* __restrict__ x, int n4, unsigned* __restrict__ xb,
                                              unsigned* __restrict__ xq,
                                              const int* __restrict__ dst, int E,
                                              int* __restrict__ bcnt, int nbuck,
                                              int castBlocks, int histBlocks,
                                              WtpArgs a0, WtpArgs a1, WtpArgs a2, WtpArgs a3){
  __shared__ int s[NBUCK_MAX];
  int b = blockIdx.x, t = threadIdx.x;
  if (b < castBlocks){
    int i = b*256 + t;            // i over groups of 4 floats
    if (i < n4){
      float4 v = ((const float4*)x)[i];
      uint2 o; o.x = pack2(v.x, v.y); o.y = pack2(v.z, v.w);
      ((uint2*)xb)[i] = o;
      xq[i] = pk_fp8x4(v.x, v.y, v.z, v.w);    // identity channel order
    }
    return;
  }
  b -= castBlocks;
  if (b < histBlocks){
    for (int i=t;i<nbuck;i+=256) s[i] = 0;
    __syncthreads();
    constexpr int EPT = 16;
    int e0 = b*256*EPT;
    #pragma unroll
    for (int i=0;i<EPT;i++){
      int e = e0 + i*256 + t;
      if (e < E) atomicAdd(&s[dst[e] >> 7], 1);
    }
    __syncthreads();
    for (int i=t;i<nbuck;i+=256){
      int c = s[i];
      if (c > 0) atomicAdd(&bcnt[i], c);
    }
    return;
  }
  b -= histBlocks;
  if (b < a0.nblk){ wtp_one(a0, b*256 + t); return; }
  b -= a0.nblk;
  if (b < a1.nblk){ wtp_one(a1, b*256 + t); return; }
  b -= a1.nblk;
  if (b < a2.nblk){ wtp_one(a2, b*256 + t); return; }
  b -= a2.nblk;
  wtp_one(a3, b*256 + t);
}

// single block: exclusive scan of bcnt[0..nbuck) -> bbase[0..nbuck], bbase[nbuck]=E
__global__ __launch_bounds__(256) void k_bscan(const int* __restrict__ bcnt, int nbuck,
                                               int* __restrict__ bbase){
  __shared__ int s[256];
  int t = threadIdx.x;
  int a0 = (2*t   < nbuck) ? bcnt[2*t]   : 0;
  int a1 = (2*t+1 < nbuck) ? bcnt[2*t+1] : 0;
  s[t] = a0 + a1; __syncthreads();
  for (int d=1; d<256; d<<=1){
    int u = (t>=d) ? s[t-d] : 0;
    __syncthreads();
    s[t] += u;
    __syncthreads();
  }
  int excl = s[t] - (a0 + a1);
  if (2*t   < nbuck) bbase[2*t]   = excl;
  if (2*t+1 < nbuck) bbase[2*t+1] = excl + a0;
  if (t == 255) bbase[nbuck] = s[255];
}

// Pass A: bin edges into 128-node buckets; bucket region in ebuf == final csr region.
// Packed entry: (local_dst << 16) | src  (requires N <= 65536)
__global__ __launch_bounds__(256) void k_bucketA(const int* __restrict__ src, const int* __restrict__ dst,
                                                 int E, const int* __restrict__ bbase,
                                                 int* __restrict__ bcur, unsigned* __restrict__ ebuf, int nbuck){
  __shared__ int scnt[NBUCK_MAX];
  __shared__ int sbase[NBUCK_MAX];
  __shared__ int sboff[NBUCK_MAX];
  int t = threadIdx.x;
  for (int i=t;i<nbuck;i+=256) scnt[i] = 0;
  __syncthreads();
  constexpr int EPT = 16;
  int e0 = blockIdx.x*256*EPT;
  int b[EPT]; unsigned pk[EPT];
  #pragma unroll
  for (int i=0;i<EPT;i++){
    int e = e0 + i*256 + t;
    if (e < E){
      int d = dst[e];
      b[i] = d >> 7;
      pk[i] = ((unsigned)(d & 127) << 16) | (unsigned)src[e];
      atomicAdd(&scnt[b[i]], 1);
    } else b[i] = -1;
  }
  __syncthreads();
  for (int i=t;i<nbuck;i+=256){
    int c = scnt[i];
    sbase[i] = (c > 0) ? atomicAdd(&bcur[i], c) : 0;
    sboff[i] = bbase[i];
    scnt[i] = 0;
  }
  __syncthreads();
  #pragma unroll
  for (int i=0;i<EPT;i++){
    if (b[i] >= 0){
      int p = atomicAdd(&scnt[b[i]], 1);
      ebuf[(size_t)sboff[b[i]] + sbase[b[i]] + p] = pk[i];
    }
  }
}

// Pass B: one block per bucket; local degree count + scan -> off + csr scatter in ~8KB window.
__global__ __launch_bounds__(256) void k_bucketB(const unsigned* __restrict__ ebuf, const int* __restrict__ bbase,
                                                 int N, int* __restrict__ off, int* __restrict__ csr){
  int b = blockIdx.x;
  int n0 = b << 7, n1 = min(n0 + 128, N);
  __shared__ int sdeg[128];
  __shared__ int sabs[129];
  __shared__ int cur[128];
  int t = threadIdx.x;
  if (t < 128){ sdeg[t] = 0; cur[t] = 0; }
  __syncthreads();
  int e0 = bbase[b], e1 = bbase[b+1];
  for (int e = e0 + t; e < e1; e += 256)
    atomicAdd(&sdeg[ebuf[e] >> 16], 1);
  __syncthreads();
  for (int d=1; d<128; d<<=1){
    int u = (t < 128 && t >= d) ? sdeg[t-d] : 0;
    __syncthreads();
    if (t < 128) sdeg[t] += u;
    __syncthreads();
  }
  if (t == 0) sabs[0] = e0;
  if (t < 128) sabs[t+1] = e0 + sdeg[t];
  __syncthreads();
  if (t <= n1 - n0) off[n0 + t] = sabs[t];
  for (int e = e0 + t; e < e1; e += 256){
    unsigned pr = ebuf[e];
    int ln = (int)(pr >> 16);
    int p = atomicAdd(&cur[ln], 1);
    csr[sabs[ln] + p] = (int)(pr & 0xffffu);
  }
}

// ---------------- mean aggregation, 128-dim fp8 rows: 8 nodes/wave, 8 lanes x uint4, LDS-staged csr ----------------
// position-agnostic: averages byte-positions; output bf16 at the SAME positions.

__global__ __launch_bounds__(256) void k_agg(const uint4* __restrict__ hq4, const int* __restrict__ off,
                                             const int* __restrict__ csr, int n, uint4* __restrict__ mean4){
  __shared__ int scsr[AGG_CAP];
  __shared__ int sw[2];
  int t = threadIdx.x;
  int nodeblk = blockIdx.x * 32;
  if (t < 2) sw[t] = off[min(nodeblk + t*32, n)];
  __syncthreads();
  int e0b = sw[0];
  int span = sw[1] - e0b;
  for (int i = t; i < span && i < AGG_CAP; i += 256) scsr[i] = csr[e0b + i];
  __syncthreads();

  int lane = t & 63;
  int sl = lane & 7;
  int node = nodeblk + (t >> 3);
  bool valid = node < n;
  int s0 = valid ? off[node]   : 0;
  int s1 = valid ? off[node+1] : 0;
  float a0=0,a1=0,a2=0,a3=0,a4=0,a5=0,a6=0,a7=0;
  float a8=0,a9=0,a10=0,a11=0,a12=0,a13=0,a14=0,a15=0;
  int e = s0;
  for (; e + 8 <= s1; e += 8){
    int le = e - e0b;
    int i0,i1,i2,i3,i4,i5,i6,i7;
    if (le + 8 <= AGG_CAP){
      i0 = scsr[le];   i1 = scsr[le+1]; i2 = scsr[le+2]; i3 = scsr[le+3];
      i4 = scsr[le+4]; i5 = scsr[le+5]; i6 = scsr[le+6]; i7 = scsr[le+7];
    } else {
      i0 = csr[e];   i1 = csr[e+1]; i2 = csr[e+2]; i3 = csr[e+3];
      i4 = csr[e+4]; i5 = csr[e+5]; i6 = csr[e+6]; i7 = csr[e+7];
    }
    uint4 v0 = hq4[(size_t)i0*8 + sl];
    uint4 v1 = hq4[(size_t)i1*8 + sl];
    uint4 v2 = hq4[(size_t)i2*8 + sl];
    uint4 v3 = hq4[(size_t)i3*8 + sl];
    uint4 v4 = hq4[(size_t)i4*8 + sl];
    uint4 v5 = hq4[(size_t)i5*8 + sl];
    uint4 v6 = hq4[(size_t)i6*8 + sl];
    uint4 v7 = hq4[(size_t)i7*8 + sl];
    ACCQ16(v0); ACCQ16(v1); ACCQ16(v2); ACCQ16(v3);
    ACCQ16(v4); ACCQ16(v5); ACCQ16(v6); ACCQ16(v7);
  }
  for (; e + 4 <= s1; e += 4){
    int le = e - e0b;
    int i0,i1,i2,i3;
    if (le + 4 <= AGG_CAP){
      i0 = scsr[le]; i1 = scsr[le+1]; i2 = scsr[le+2]; i3 = scsr[le+3];
    } else {
      i0 = csr[e]; i1 = csr[e+1]; i2 = csr[e+2]; i3 = csr[e+3];
    }
    uint4 v0 = hq4[(size_t)i0*8 + sl];
    uint4 v1 = hq4[(size_t)i1*8 + sl];
    uint4 v2 = hq4[(size_t)i2*8 + sl];
    uint4 v3 = hq4[(size_t)i3*8 + sl];
    ACCQ16(v0); ACCQ16(v1); ACCQ16(v2); ACCQ16(v3);
  }
  for (; e < s1; e++){
    int le = e - e0b;
    int ii = (le < AGG_CAP) ? scsr[le] : csr[e];
    uint4 v = hq4[(size_t)ii*8 + sl];
    ACCQ16(v);
  }
  if (valid){
    int d = s1 - s0;
    float inv = 1.0f / (float)(d > 0 ? d : 1);
    uint4 o0, o1;
    o0.x = pack2(a0*inv,  a1*inv);  o0.y = pack2(a2*inv,  a3*inv);
    o0.z = pack2(a4*inv,  a5*inv);  o0.w = pack2(a6*inv,  a7*inv);
    o1.x = pack2(a8*inv,  a9*inv);  o1.y = pack2(a10*inv, a11*inv);
    o1.z = pack2(a12*inv, a13*inv); o1.w = pack2(a14*inv, a15*inv);
    size_t base = (size_t)node*16 + (size_t)sl*2;
    mean4[base]   = o0;
    mean4[base+1] = o1;
  }
}

// ---------------- hidden-layer GEMM (LDS-staged B, round-4 structure), optional fused yl mini-GEMM ----------------
// C[N][128] = [A0|A1]@B (K=256), BN+ReLU, bf16 out (+ fp8(perm) copy when !YL).
// If YL: also yl = C@Wl2^T (K=128, DOUT=64) -> outyl as fp8(perm2).

template<bool YL>
__global__ __launch_bounds__(256, 2) void k_gemm_hid(
    const unsigned short* __restrict__ A0, const unsigned short* __restrict__ A1,
    const unsigned short* __restrict__ Bpk, const float* __restrict__ sc,
    const float* __restrict__ sh, const unsigned short* __restrict__ BpkL,
    unsigned short* __restrict__ outh, unsigned* __restrict__ outq,
    unsigned* __restrict__ outyl, int n){
  __shared__ unsigned short Bs[256*128];   // 64 KB
  int t = threadIdx.x;
  {
    const uint4* s = (const uint4*)Bpk;
    uint4* d = (uint4*)Bs;
    #pragma unroll
    for (int i=0;i<16;i++) d[i*256 + t] = s[i*256 + t];
  }
  __syncthreads();

  int lane = t & 63, w = t >> 6;
  int quad = lane >> 4, c = lane & 15;
  int mb = blockIdx.x*128, woff = w*32;
  int r0 = mb + woff + c;
  int r1 = r0 + 16;

  f32x4 acc[2][8];
  #pragma unroll
  for (int mt=0;mt<2;mt++)
    #pragma unroll
    for (int nt=0;nt<8;nt++) acc[mt][nt] = (f32x4){0.f,0.f,0.f,0.f};

  #pragma unroll
  for (int kk=0; kk<8; kk++){
    const unsigned short* ab = (kk >= 4) ? A1 : A0;
    int ka = (kk & 3)*32 + quad*8;
    short8 a0 = {0,0,0,0,0,0,0,0}, a1 = {0,0,0,0,0,0,0,0};
    if (r0 < n) a0 = *(const short8*)(ab + (size_t)r0*128 + ka);
    if (r1 < n) a1 = *(const short8*)(ab + (size_t)r1*128 + ka);
    #pragma unroll
    for (int nt=0; nt<8; nt++){
      short8 b = *(const short8*)&Bs[(size_t)((kk*8 + nt)*64 + lane)*8];
      acc[0][nt] = __builtin_amdgcn_mfma_f32_16x16x32_bf16(a0, b, acc[0][nt], 0, 0, 0);
      acc[1][nt] = __builtin_amdgcn_mfma_f32_16x16x32_bf16(a1, b, acc[1][nt], 0, 0, 0);
    }
  }

  float scv[8], shv[8];
  #pragma unroll
  for (int nt=0;nt<8;nt++){ scv[nt] = sc[nt*16 + c]; shv[nt] = sh[nt*16 + c]; }

  #pragma unroll
  for (int mt=0; mt<2; mt++){
    #pragma unroll
    for (int r=0;r<4;r++){
      int row = mb + woff + mt*16 + quad*4 + r;
      if (row < n){
        float u[8];
        #pragma unroll
        for (int nt=0;nt<8;nt++){
          float uu = acc[mt][nt][r]*scv[nt] + shv[nt];
          u[nt] = fmaxf(uu, 0.f);
          outh[(size_t)row*128 + nt*16 + c] = f2bf(u[nt]);
        }
        if constexpr (!YL){
          // fp8(perm) copy for the next layer's gather: bytes row*128 + c*8 + j hold channel j*16+c
          uint2 q;
          q.x = pk_fp8x4(u[0], u[1], u[2], u[3]);
          q.y = pk_fp8x4(u[4], u[5], u[6], u[7]);
          ((uint2*)outq)[(size_t)row*16 + c] = q;
        }
      }
    }
  }

  if constexpr (YL){
    __syncthreads();   // everyone done reading Bs; outh tile visible block-wide after barrier
    {
      // restage own h tile (128 rows x 128 bf16 = 2048 uint4) into Bs[0..16384)
      uint4* d = (uint4*)Bs;
      const uint4* s4 = (const uint4*)outh;
      #pragma unroll
      for (int i=0;i<8;i++){
        int idx = i*256 + t;
        int row = idx >> 4;
        int gr = mb + row; if (gr > n-1) gr = n-1;
        d[idx] = s4[(size_t)gr*16 + (idx & 15)];
      }
      // stage BpkL (128x64 = 1024 uint4) at short-offset 16384
      const uint4* sL = (const uint4*)BpkL;
      #pragma unroll
      for (int i=0;i<4;i++) d[2048 + i*256 + t] = sL[i*256 + t];
    }
    __syncthreads();
    f32x4 acc2[2][4];
    #pragma unroll
    for (int mt=0;mt<2;mt++)
      #pragma unroll
      for (int nt=0;nt<4;nt++) acc2[mt][nt] = (f32x4){0.f,0.f,0.f,0.f};
    int r0l = woff + c, r1l = r0l + 16;
    #pragma unroll
    for (int kk=0; kk<4; kk++){
      int ka = kk*32 + quad*8;
      short8 a0 = *(const short8*)&Bs[(size_t)r0l*128 + ka];
      short8 a1 = *(const short8*)&Bs[(size_t)r1l*128 + ka];
      #pragma unroll
      for (int nt=0; nt<4; nt++){
        short8 b = *(const short8*)&Bs[16384 + (size_t)((kk*4 + nt)*64 + lane)*8];
        acc2[0][nt] = __builtin_amdgcn_mfma_f32_16x16x32_bf16(a0, b, acc2[0][nt], 0, 0, 0);
        acc2[1][nt] = __builtin_amdgcn_mfma_f32_16x16x32_bf16(a1, b, acc2[1][nt], 0, 0, 0);
      }
    }
    #pragma unroll
    for (int mt=0; mt<2; mt++){
      #pragma unroll
      for (int r=0;r<4;r++){
        int row = mb + woff + mt*16 + quad*4 + r;
        if (row < n){
          // fp8(perm2): byte row*64 + c*4 + nt holds channel nt*16+c
          unsigned q = pk_fp8x4(acc2[0][0][r], acc2[0][1][r], acc2[0][2][r], acc2[0][3][r]);
          unsigned q1 = pk_fp8x4(acc2[1][0][r], acc2[1][1][r], acc2[1][2][r], acc2[1][3][r]);
          outyl[(size_t)row*16 + c] = (mt == 0) ? q : q1;
        }
      }
    }
  }
}

// ---------------- fused layer-3: mean-yl gather (64-dim fp8, uint4 lanes, LDS csr) + GEMM + BN + L2norm ----------------

__global__ __launch_bounds__(256, 2) void k_aggf(
    const uint4* __restrict__ ylq4, const int* __restrict__ off, const int* __restrict__ csr,
    const unsigned short* __restrict__ A0, const unsigned short* __restrict__ BpkR,
    const float* __restrict__ sc, const float* __restrict__ sh,
    float* __restrict__ outf, int n){
  __shared__ unsigned short Ms[128*64];   // 16 KB mean-yl tile (bf16, perm2 positions)
  __shared__ unsigned short Bs[128*64];   // 16 KB BpkR
  __shared__ int scsr[AGGF_CAP];          // 12 KB staged csr window
  __shared__ int sw[2];
  int t = threadIdx.x;
  int mb = blockIdx.x*128;
  if (t < 2) sw[t] = off[min(mb + t*128, n)];
  {
    const uint4* s = (const uint4*)BpkR;
    uint4* d = (uint4*)Bs;
    #pragma unroll
    for (int i=0;i<4;i++) d[i*256 + t] = s[i*256 + t];
  }
  __syncthreads();
  int e0b = sw[0];
  int span = sw[1] - e0b;
  for (int i = t; i < span && i < AGGF_CAP; i += 256) scsr[i] = csr[e0b + i];
  __syncthreads();

  int lane = t & 63, w = t >> 6;
  int sl4 = lane & 3;

  // gather phase: wave w covers local rows [w*32, w*32+32), 16 nodes at a time, 4 lanes x uint4 each
  #pragma unroll
  for (int it=0; it<2; it++){
    int ln = w*32 + it*16 + (lane >> 2);
    int node = mb + ln;
    bool valid = node < n;
    int s0 = valid ? off[node]   : 0;
    int s1 = valid ? off[node+1] : 0;
    float a0=0,a1=0,a2=0,a3=0,a4=0,a5=0,a6=0,a7=0;
    float a8=0,a9=0,a10=0,a11=0,a12=0,a13=0,a14=0,a15=0;
    int e = s0;
    for (; e + 8 <= s1; e += 8){
      int le = e - e0b;
      int i0,i1,i2,i3,i4,i5,i6,i7;
      if (le + 8 <= AGGF_CAP){
        i0 = scsr[le];   i1 = scsr[le+1]; i2 = scsr[le+2]; i3 = scsr[le+3];
        i4 = scsr[le+4]; i5 = scsr[le+5]; i6 = scsr[le+6]; i7 = scsr[le+7];
      } else {
        i0 = csr[e];   i1 = csr[e+1]; i2 = csr[e+2]; i3 = csr[e+3];
        i4 = csr[e+4]; i5 = csr[e+5]; i6 = csr[e+6]; i7 = csr[e+7];
      }
      uint4 v0 = ylq4[(size_t)i0*4 + sl4];
      uint4 v1 = ylq4[(size_t)i1*4 + sl4];
      uint4 v2 = ylq4[(size_t)i2*4 + sl4];
      uint4 v3 = ylq4[(size_t)i3*4 + sl4];
      uint4 v4 = ylq4[(size_t)i4*4 + sl4];
      uint4 v5 = ylq4[(size_t)i5*4 + sl4];
      uint4 v6 = ylq4[(size_t)i6*4 + sl4];
      uint4 v7 = ylq4[(size_t)i7*4 + sl4];
      ACCQ16(v0); ACCQ16(v1); ACCQ16(v2); ACCQ16(v3);
      ACCQ16(v4); ACCQ16(v5); ACCQ16(v6); ACCQ16(v7);
    }
    for (; e + 4 <= s1; e += 4){
      int le = e - e0b;
      int i0,i1,i2,i3;
      if (le + 4 <= AGGF_CAP){
        i0 = scsr[le]; i1 = scsr[le+1]; i2 = scsr[le+2]; i3 = scsr[le+3];
      } else {
        i0 = csr[e]; i1 = csr[e+1]; i2 = csr[e+2]; i3 = csr[e+3];
      }
      uint4 v0 = ylq4[(size_t)i0*4 + sl4];
      uint4 v1 = ylq4[(size_t)i1*4 + sl4];
      uint4 v2 = ylq4[(size_t)i2*4 + sl4];
      uint4 v3 = ylq4[(size_t)i3*4 + sl4];
      ACCQ16(v0); ACCQ16(v1); ACCQ16(v2); ACCQ16(v3);
    }
    for (; e < s1; e++){
      int le = e - e0b;
      int ii = (le < AGGF_CAP) ? scsr[le] : csr[e];
      uint4 v = ylq4[(size_t)ii*4 + sl4];
      ACCQ16(v);
    }
    int d = s1 - s0;
    float inv = 1.0f / (float)(d > 0 ? d : 1);
    uint4 o0, o1;
    o0.x = pack2(a0*inv,  a1*inv);  o0.y = pack2(a2*inv,  a3*inv);
    o0.z = pack2(a4*inv,  a5*inv);  o0.w = pack2(a6*inv,  a7*inv);
    o1.x = pack2(a8*inv,  a9*inv);  o1.y = pack2(a10*inv, a11*inv);
    o1.z = pack2(a12*inv, a13*inv); o1.w = pack2(a14*inv, a15*inv);
    ((uint4*)Ms)[ln*8 + sl4*2]     = o0;
    ((uint4*)Ms)[ln*8 + sl4*2 + 1] = o1;
  }
  __syncthreads();

  // GEMM phase: C = h_b @ Wr2^T (K=128), + mean-yl, BN, L2-normalize
  int quad = lane >> 4, c = lane & 15;
  int woff = w*32;
  int r0 = mb + woff + c;
  int r1 = r0 + 16;
  f32x4 acc[2][4];
  #pragma unroll
  for (int mt=0;mt<2;mt++)
    #pragma unroll
    for (int nt=0;nt<4;nt++) acc[mt][nt] = (f32x4){0.f,0.f,0.f,0.f};
  #pragma unroll
  for (int kk=0; kk<4; kk++){
    int ka = kk*32 + quad*8;
    short8 a0 = {0,0,0,0,0,0,0,0}, a1 = {0,0,0,0,0,0,0,0};
    if (r0 < n) a0 = *(const short8*)(A0 + (size_t)r0*128 + ka);
    if (r1 < n) a1 = *(const short8*)(A0 + (size_t)r1*128 + ka);
    #pragma unroll
    for (int nt=0; nt<4; nt++){
      short8 b = *(const short8*)&Bs[(size_t)((kk*4 + nt)*64 + lane)*8];
      acc[0][nt] = __builtin_amdgcn_mfma_f32_16x16x32_bf16(a0, b, acc[0][nt], 0, 0, 0);
      acc[1][nt] = __builtin_amdgcn_mfma_f32_16x16x32_bf16(a1, b, acc[1][nt], 0, 0, 0);
    }
  }

  float scv[4], shv[4];
  #pragma unroll
  for (int nt=0;nt<4;nt++){ scv[nt] = sc[nt*16 + c]; shv[nt] = sh[nt*16 + c]; }

  #pragma unroll
  for (int mt=0; mt<2; mt++){
    #pragma unroll
    for (int r=0;r<4;r++){
      int lr = woff + mt*16 + quad*4 + r;
      int row = mb + lr;
      float v[4];
      float ss = 0.f;
      if (row < n){
        #pragma unroll
        for (int nt=0;nt<4;nt++){
          // Ms holds perm2 positions: channel nt*16+c lives at position c*4+nt
          float u = acc[mt][nt][r] + bf2f(Ms[lr*64 + c*4 + nt]);
          u = u*scv[nt] + shv[nt];
          v[nt] = u;
          ss += u*u;
        }
      } else {
        #pragma unroll
        for (int nt=0;nt<4;nt++) v[nt] = 0.f;
      }
      ss += __shfl_xor(ss, 1, 64);
      ss += __shfl_xor(ss, 2, 64);
      ss += __shfl_xor(ss, 4, 64);
      ss += __shfl_xor(ss, 8, 64);
      float rn = 1.0f / fmaxf(sqrtf(ss), 1e-12f);
      if (row < n){
        #pragma unroll
        for (int nt=0;nt<4;nt++) outf[(size_t)row*64 + nt*16 + c] = v[nt]*rn;
      }
    }
  }
}

// ---------------- launcher ----------------

extern "C" void kernel_launch(void* const* d_in, const int* in_sizes, int n_in,
                              void* d_out, int out_size, void* d_ws, size_t ws_size,
                              hipStream_t stream){
  const float* x = (const float*)d_in[0];
  const int* ei  = (const int*)d_in[1];
  int N = in_sizes[0] / 128;
  int E = in_sizes[1] / 2;
  const int* esrc = ei;
  const int* edst = ei + E;
  int nbuck = CDIV(N, 128);

  const float *Wl[3], *bl[3], *Wr[3], *g[3], *bb[3], *rm[3], *rv[3];
  int dout[3];
  for (int i=0;i<3;i++){
    int base = 2 + 7*i;
    Wl[i]=(const float*)d_in[base];   bl[i]=(const float*)d_in[base+1];
    Wr[i]=(const float*)d_in[base+2]; g[i] =(const float*)d_in[base+3];
    bb[i]=(const float*)d_in[base+4]; rm[i]=(const float*)d_in[base+5];
    rv[i]=(const float*)d_in[base+6];
    dout[i] = in_sizes[base] / 128;
  }

  char* p = (char*)d_ws;
  size_t o = 0;
  auto alloc = [&](size_t bytes)->void*{ void* r = p + o; o += (bytes + 255) & ~(size_t)255; return r; };
  int* bz    = (int*)alloc((size_t)2*nbuck*4);   // bcnt | bcur (one memset)
  int* bcnt  = bz;
  int* bcur  = bz + nbuck;
  int* bbase = (int*)alloc((size_t)(nbuck+1)*4);
  int* off   = (int*)alloc((size_t)(N+1)*4);
  int* csr   = (int*)alloc((size_t)E*4);
  unsigned* ebuf = (unsigned*)alloc((size_t)E*4);
  unsigned* xb   = (unsigned*)alloc((size_t)N*64*4);   // bf16 x (natural)
  unsigned* xq   = (unsigned*)alloc((size_t)N*128);    // fp8 x (identity order)
  unsigned* mb   = (unsigned*)alloc((size_t)N*64*4);   // bf16 mean (position pass-through)
  unsigned* h_a  = (unsigned*)alloc((size_t)N*64*4);   // bf16 h1 (natural)
  unsigned* haq  = (unsigned*)alloc((size_t)N*128);    // fp8 h1 (perm)
  unsigned* h_b  = (unsigned*)alloc((size_t)N*64*4);   // bf16 h2 (natural)
  unsigned* ylb  = (unsigned*)alloc((size_t)N*64);     // fp8 yl (perm2)
  unsigned short* Bpk01[2];
  float* sc[3]; float* sh[3];
  for (int i=0;i<2;i++) Bpk01[i] = (unsigned short*)alloc((size_t)256*dout[i]*2);
  unsigned short* BpkL = (unsigned short*)alloc((size_t)128*dout[2]*2);
  unsigned short* BpkR = (unsigned short*)alloc((size_t)128*dout[2]*2);
  for (int i=0;i<3;i++){
    sc[i] = (float*)alloc((size_t)dout[i]*4);
    sh[i] = (float*)alloc((size_t)dout[i]*4);
  }

  hipMemsetAsync(bz, 0, (size_t)2*nbuck*4, stream);

  WtpArgs wa[4];
  wa[0] = { Wl[0], Wr[0], bl[0], g[0], bb[0], rm[0], rv[0], Bpk01[0], sc[0], sh[0], 8, dout[0], 1, CDIV(256*dout[0]+dout[0],256), 0 };
  wa[1] = { Wl[1], Wr[1], bl[1], g[1], bb[1], rm[1], rv[1], Bpk01[1], sc[1], sh[1], 8, dout[1], 1, CDIV(256*dout[1]+dout[1],256), 1 };
  wa[2] = { Wl[2], nullptr, nullptr, nullptr, nullptr, nullptr, nullptr, BpkL, nullptr, nullptr, 4, dout[2], 0, CDIV(128*dout[2],256), 0 };
  wa[3] = { Wr[2], nullptr, bl[2], g[2], bb[2], rm[2], rv[2], BpkR, sc[2], sh[2], 4, dout[2], 1, CDIV(128*dout[2]+dout[2],256), 0 };

  int castBlocks = CDIV(N*32, 256);
  int histBlocks = CDIV(E, 256*16);
  int prepBlocks = castBlocks + histBlocks + wa[0].nblk + wa[1].nblk + wa[2].nblk + wa[3].nblk;
  k_prep   <<<prepBlocks,256,0,stream>>>(x, N*32, xb, xq, edst, E, bcnt, nbuck, castBlocks, histBlocks,
                                         wa[0], wa[1], wa[2], wa[3]);
  k_bscan  <<<1,256,0,stream>>>(bcnt, nbuck, bbase);
  k_bucketA<<<CDIV(E,256*16),256,0,stream>>>(esrc, edst, E, bbase, bcur, ebuf, nbuck);
  k_bucketB<<<nbuck,256,0,stream>>>(ebuf, bbase, N, off, csr);

  // layer 0
  k_agg<<<CDIV(N,32),256,0,stream>>>((const uint4*)xq, off, csr, N, (uint4*)mb);
  k_gemm_hid<false><<<CDIV(N,128),256,0,stream>>>((const unsigned short*)mb, (const unsigned short*)xb,
                                                  Bpk01[0], sc[0], sh[0], nullptr,
                                                  (unsigned short*)h_a, haq, nullptr, N);
  // layer 1 (+ fused yl = h_b @ Wl2^T, emitted as fp8 perm2)
  k_agg<<<CDIV(N,32),256,0,stream>>>((const uint4*)haq, off, csr, N, (uint4*)mb);
  k_gemm_hid<true><<<CDIV(N,128),256,0,stream>>>((const unsigned short*)mb, (const unsigned short*)h_a,
                                                 Bpk01[1], sc[1], sh[1], BpkL,
                                                 (unsigned short*)h_b, nullptr, ylb, N);
  // layer 2: fused mean-yl gather + final GEMM + BN + L2norm
  k_aggf<<<CDIV(N,128),256,0,stream>>>((const uint4*)ylb, off, csr,
                                       (const unsigned short*)h_b, BpkR, sc[2], sh[2],
                                       (float*)d_out, N);
}

// Round 3
// 239.138 us; speedup vs baseline: 1.1224x; 1.0043x over previous
//
#include <hip/hip_runtime.h>
#include <hip/hip_bf16.h>

#define CDIV(a,b) (((a)+(b)-1)/(b))
#define NBUCK_MAX 512   // buckets of 128 nodes; supports N up to 65536 (ebuf packing needs N<=65536)
#define AGG_CAP  1536   // staged csr entries per k_agg block (32 nodes)
#define AGGF_CAP 3072   // staged csr entries per k_aggf block (128 nodes)

typedef __attribute__((ext_vector_type(8))) short short8;
typedef __attribute__((ext_vector_type(4))) float f32x4;
typedef __attribute__((ext_vector_type(2))) float f32x2;

static __device__ __forceinline__ unsigned short f2bf(float f){
  union { float f; unsigned u; } v; v.f = f;
  unsigned r = v.u + 0x7fffu + ((v.u >> 16) & 1u);   // RNE
  return (unsigned short)(r >> 16);
}
static __device__ __forceinline__ unsigned pack2(float lo, float hi){
  return (unsigned)f2bf(lo) | ((unsigned)f2bf(hi) << 16);
}
static __device__ __forceinline__ float bf2f(unsigned short s){
  union { unsigned u; float f; } v; v.u = ((unsigned)s) << 16; return v.f;
}
// pack 4 f32 -> 4 fp8 e4m3 bytes (byte0=a .. byte3=d)
static __device__ __forceinline__ unsigned pk_fp8x4(float a, float b, float c, float d){
  int v = __builtin_amdgcn_cvt_pk_fp8_f32(a, b, 0, false);
  v = __builtin_amdgcn_cvt_pk_fp8_f32(c, d, v, true);
  return (unsigned)v;
}

// accumulate 16 fp8 bytes (uint4) into f32x2 accumulators b0..b7 (v_pk_add_f32 path)
#define ACCP16(v) { b0 += __builtin_amdgcn_cvt_pk_f32_fp8((int)v.x, false); \
                    b1 += __builtin_amdgcn_cvt_pk_f32_fp8((int)v.x, true);  \
                    b2 += __builtin_amdgcn_cvt_pk_f32_fp8((int)v.y, false); \
                    b3 += __builtin_amdgcn_cvt_pk_f32_fp8((int)v.y, true);  \
                    b4 += __builtin_amdgcn_cvt_pk_f32_fp8((int)v.z, false); \
                    b5 += __builtin_amdgcn_cvt_pk_f32_fp8((int)v.z, true);  \
                    b6 += __builtin_amdgcn_cvt_pk_f32_fp8((int)v.w, false); \
                    b7 += __builtin_amdgcn_cvt_pk_f32_fp8((int)v.w, true); }

// ---------------- weight pack args ----------------
// perm: first-128 K positions hold channel pi(k) = (k&7)*16 + (k>>3) (matches gemm-epilogue fp8 row layout)

struct WtpArgs {
  const float *W0, *W1, *bl, *g, *b, *rm, *rv;
  unsigned short* Bpk; float *sc; float *sh;
  int kblk, dout, do_bn, nblk, perm;
};

static __device__ __forceinline__ void wtp_one(const WtpArgs& a, int idx){
  int NB16 = a.kblk*32*a.dout;
  if (idx < NB16){
    int j = idx & 7, lane = (idx >> 3) & 63, rest = idx >> 9;
    int NT = a.dout >> 4;
    int nt = rest % NT, kk = rest / NT;
    int nn = nt*16 + (lane & 15);
    int k  = kk*32 + ((lane >> 4) * 8) + j;
    float v;
    if (k < 128){
      int kc = a.perm ? (((k & 7) << 4) | (k >> 3)) : k;
      v = a.W0[nn*128 + kc];
    } else {
      v = a.W1[nn*128 + (k - 128)];
    }
    a.Bpk[idx] = f2bf(v);
  } else if (a.do_bn && idx < NB16 + a.dout){
    int jj = idx - NB16;
    float s = a.g[jj] * rsqrtf(a.rv[jj] + 1e-5f);
    a.sc[jj] = s;
    a.sh[jj] = (a.bl[jj] - a.rm[jj]) * s + a.b[jj];
  }
}

// ---------------- prep: cast x->bf16 + x->fp8(identity) in one pass | bucket histogram | weight pack ----------------

__global__ __launch_bounds__(256) void k_prep(const float* __restrict__ x, int n4, unsigned* __restrict__ xb,
                                              unsigned* __restrict__ xq,
                                              const int* __restrict__ dst, int E,
                                              int* __restrict__ bcnt, int nbuck,
                                              int castBlocks, int histBlocks,
                                              WtpArgs a0, WtpArgs a1, WtpArgs a2, WtpArgs a3){
  __shared__ int s[NBUCK_MAX];
  int b = blockIdx.x, t = threadIdx.x;
  if (b < castBlocks){
    int i = b*256 + t;            // i over groups of 4 floats
    if (i < n4){
      float4 v = ((const float4*)x)[i];
      uint2 o; o.x = pack2(v.x, v.y); o.y = pack2(v.z, v.w);
      ((uint2*)xb)[i] = o;
      xq[i] = pk_fp8x4(v.x, v.y, v.z, v.w);    // identity channel order
    }
    return;
  }
  b -= castBlocks;
  if (b < histBlocks){
    for (int i=t;i<nbuck;i+=256) s[i] = 0;
    __syncthreads();
    constexpr int EPT = 16;
    int e0 = b*256*EPT;
    #pragma unroll
    for (int i=0;i<EPT;i++){
      int e = e0 + i*256 + t;
      if (e < E) atomicAdd(&s[dst[e] >> 7], 1);
    }
    __syncthreads();
    for (int i=t;i<nbuck;i+=256){
      int c = s[i];
      if (c > 0) atomicAdd(&bcnt[i], c);
    }
    return;
  }
  b -= histBlocks;
  if (b < a0.nblk){ wtp_one(a0, b*256 + t); return; }
  b -= a0.nblk;
  if (b < a1.nblk){ wtp_one(a1, b*256 + t); return; }
  b -= a1.nblk;
  if (b < a2.nblk){ wtp_one(a2, b*256 + t); return; }
  b -= a2.nblk;
  wtp_one(a3, b*256 + t);
}

// Pass A: bin edges into 128-node buckets; bucket region in ebuf == final csr region.
// Per-block LDS scan of bcnt replaces the separate k_bscan kernel.
// Packed entry: (local_dst << 16) | src  (requires N <= 65536)
__global__ __launch_bounds__(256) void k_bucketA(const int* __restrict__ src, const int* __restrict__ dst,
                                                 int E, const int* __restrict__ bcnt,
                                                 int* __restrict__ bcur, unsigned* __restrict__ ebuf, int nbuck){
  __shared__ int scnt[NBUCK_MAX];
  __shared__ int sbase[NBUCK_MAX];
  __shared__ int sboff[NBUCK_MAX];
  __shared__ int ss[256];
  int t = threadIdx.x;
  // exclusive scan of bcnt -> sboff
  {
    int a0 = (2*t   < nbuck) ? bcnt[2*t]   : 0;
    int a1 = (2*t+1 < nbuck) ? bcnt[2*t+1] : 0;
    ss[t] = a0 + a1; __syncthreads();
    for (int d=1; d<256; d<<=1){
      int u = (t>=d) ? ss[t-d] : 0;
      __syncthreads();
      ss[t] += u;
      __syncthreads();
    }
    int excl = ss[t] - (a0 + a1);
    if (2*t   < nbuck) sboff[2*t]   = excl;
    if (2*t+1 < nbuck) sboff[2*t+1] = excl + a0;
  }
  for (int i=t;i<nbuck;i+=256) scnt[i] = 0;
  __syncthreads();
  constexpr int EPT = 16;
  int e0 = blockIdx.x*256*EPT;
  int b[EPT]; unsigned pk[EPT];
  #pragma unroll
  for (int i=0;i<EPT;i++){
    int e = e0 + i*256 + t;
    if (e < E){
      int d = dst[e];
      b[i] = d >> 7;
      pk[i] = ((unsigned)(d & 127) << 16) | (unsigned)src[e];
      atomicAdd(&scnt[b[i]], 1);
    } else b[i] = -1;
  }
  __syncthreads();
  for (int i=t;i<nbuck;i+=256){
    int c = scnt[i];
    sbase[i] = (c > 0) ? atomicAdd(&bcur[i], c) : 0;
    scnt[i] = 0;
  }
  __syncthreads();
  #pragma unroll
  for (int i=0;i<EPT;i++){
    if (b[i] >= 0){
      int p = atomicAdd(&scnt[b[i]], 1);
      ebuf[(size_t)sboff[b[i]] + sbase[b[i]] + p] = pk[i];
    }
  }
}

// Pass B: one block per bucket; degree count, DEGREE-DESCENDING bitonic sort of the 128 nodes,
// rank-ordered csr layout + offR (rank-indexed) + nodemap (rank -> node id).
__global__ __launch_bounds__(256) void k_bucketB(const unsigned* __restrict__ ebuf, const int* __restrict__ bcnt,
                                                 int nbuck, int E, int N,
                                                 int* __restrict__ offR, int* __restrict__ csr,
                                                 int* __restrict__ nodemap){
  __shared__ int sEx[NBUCK_MAX];
  __shared__ int ss[256];
  __shared__ int sdeg[128];
  __shared__ int sabs[129];
  __shared__ int cur[128];
  __shared__ unsigned skey[128];
  __shared__ int rof[128];
  int b = blockIdx.x, t = threadIdx.x;
  // exclusive scan of bcnt -> sEx
  {
    int a0 = (2*t   < nbuck) ? bcnt[2*t]   : 0;
    int a1 = (2*t+1 < nbuck) ? bcnt[2*t+1] : 0;
    ss[t] = a0 + a1; __syncthreads();
    for (int d=1; d<256; d<<=1){
      int u = (t>=d) ? ss[t-d] : 0;
      __syncthreads();
      ss[t] += u;
      __syncthreads();
    }
    int excl = ss[t] - (a0 + a1);
    if (2*t   < nbuck) sEx[2*t]   = excl;
    if (2*t+1 < nbuck) sEx[2*t+1] = excl + a0;
  }
  if (t < 128){ sdeg[t] = 0; cur[t] = 0; }
  __syncthreads();
  int e0 = sEx[b];
  int e1 = (b+1 < nbuck) ? sEx[b+1] : E;
  for (int e = e0 + t; e < e1; e += 256)
    atomicAdd(&sdeg[ebuf[e] >> 16], 1);
  __syncthreads();
  // key = (deg<<7) | (127-lid): descending sort => high degree first; ties favor small lid (real nodes before pads)
  if (t < 128) skey[t] = ((unsigned)sdeg[t] << 7) | (unsigned)(127 - t);
  __syncthreads();
  #pragma unroll
  for (int k=2; k<=128; k<<=1){
    #pragma unroll
    for (int j=k>>1; j>0; j>>=1){
      if (t < 128){
        int p = t ^ j;
        if (p > t){
          unsigned x = skey[t], y = skey[p];
          bool swap = ((t & k) == 0) ? (x < y) : (x > y);
          if (swap){ skey[t] = y; skey[p] = x; }
        }
      }
      __syncthreads();
    }
  }
  if (t < 128){
    int lid = 127 - (int)(skey[t] & 127u);
    rof[lid] = t;                       // rank of local id
    sdeg[t] = (int)(skey[t] >> 7);      // sdeg now rank-indexed (sorted degrees)
  }
  __syncthreads();
  // scan sorted degrees -> per-rank absolute starts
  for (int d=1; d<128; d<<=1){
    int u = (t < 128 && t >= d) ? sdeg[t-d] : 0;
    __syncthreads();
    if (t < 128) sdeg[t] += u;
    __syncthreads();
  }
  if (t == 0) sabs[0] = e0;
  if (t < 128) sabs[t+1] = e0 + sdeg[t];
  __syncthreads();
  int n0 = b << 7, n1 = min(n0 + 128, N);
  int cnt = n1 - n0;
  if (t <= cnt) offR[n0 + t] = sabs[t];
  if (t < cnt)  nodemap[n0 + t] = n0 + (127 - (int)(skey[t] & 127u));
  for (int e = e0 + t; e < e1; e += 256){
    unsigned pr = ebuf[e];
    int ln = (int)(pr >> 16);
    int p = atomicAdd(&cur[ln], 1);
    csr[sabs[rof[ln]] + p] = (int)(pr & 0xffffu);
  }
}

// ---------------- mean aggregation, 128-dim fp8 rows: rank slots (degree-sorted), 8 lanes x uint4, LDS csr ----------------

__global__ __launch_bounds__(256) void k_agg(const uint4* __restrict__ hq4, const int* __restrict__ offR,
                                             const int* __restrict__ csr, const int* __restrict__ nodemap,
                                             int n, uint4* __restrict__ mean4){
  __shared__ int scsr[AGG_CAP];
  __shared__ int sw[2];
  int t = threadIdx.x;
  int nodeblk = blockIdx.x * 32;
  if (t < 2) sw[t] = offR[min(nodeblk + t*32, n)];
  __syncthreads();
  int e0b = sw[0];
  int span = sw[1] - e0b;
  for (int i = t; i < span && i < AGG_CAP; i += 256) scsr[i] = csr[e0b + i];
  __syncthreads();

  int lane = t & 63;
  int sl = lane & 7;
  int idx = nodeblk + (t >> 3);        // rank slot
  bool valid = idx < n;
  int s0 = valid ? offR[idx]   : 0;
  int s1 = valid ? offR[idx+1] : 0;
  int node = valid ? nodemap[idx] : 0;
  f32x2 b0={0,0},b1={0,0},b2={0,0},b3={0,0},b4={0,0},b5={0,0},b6={0,0},b7={0,0};
  int e = s0;
  for (; e + 8 <= s1; e += 8){
    int le = e - e0b;
    int i0,i1,i2,i3,i4,i5,i6,i7;
    if (le + 8 <= AGG_CAP){
      i0 = scsr[le];   i1 = scsr[le+1]; i2 = scsr[le+2]; i3 = scsr[le+3];
      i4 = scsr[le+4]; i5 = scsr[le+5]; i6 = scsr[le+6]; i7 = scsr[le+7];
    } else {
      i0 = csr[e];   i1 = csr[e+1]; i2 = csr[e+2]; i3 = csr[e+3];
      i4 = csr[e+4]; i5 = csr[e+5]; i6 = csr[e+6]; i7 = csr[e+7];
    }
    uint4 v0 = hq4[(size_t)i0*8 + sl];
    uint4 v1 = hq4[(size_t)i1*8 + sl];
    uint4 v2 = hq4[(size_t)i2*8 + sl];
    uint4 v3 = hq4[(size_t)i3*8 + sl];
    uint4 v4 = hq4[(size_t)i4*8 + sl];
    uint4 v5 = hq4[(size_t)i5*8 + sl];
    uint4 v6 = hq4[(size_t)i6*8 + sl];
    uint4 v7 = hq4[(size_t)i7*8 + sl];
    ACCP16(v0); ACCP16(v1); ACCP16(v2); ACCP16(v3);
    ACCP16(v4); ACCP16(v5); ACCP16(v6); ACCP16(v7);
  }
  for (; e + 4 <= s1; e += 4){
    int le = e - e0b;
    int i0,i1,i2,i3;
    if (le + 4 <= AGG_CAP){
      i0 = scsr[le]; i1 = scsr[le+1]; i2 = scsr[le+2]; i3 = scsr[le+3];
    } else {
      i0 = csr[e]; i1 = csr[e+1]; i2 = csr[e+2]; i3 = csr[e+3];
    }
    uint4 v0 = hq4[(size_t)i0*8 + sl];
    uint4 v1 = hq4[(size_t)i1*8 + sl];
    uint4 v2 = hq4[(size_t)i2*8 + sl];
    uint4 v3 = hq4[(size_t)i3*8 + sl];
    ACCP16(v0); ACCP16(v1); ACCP16(v2); ACCP16(v3);
  }
  for (; e < s1; e++){
    int le = e - e0b;
    int ii = (le < AGG_CAP) ? scsr[le] : csr[e];
    uint4 v = hq4[(size_t)ii*8 + sl];
    ACCP16(v);
  }
  if (valid){
    int d = s1 - s0;
    float inv = 1.0f / (float)(d > 0 ? d : 1);
    uint4 o0, o1;
    o0.x = pack2(b0.x*inv, b0.y*inv);  o0.y = pack2(b1.x*inv, b1.y*inv);
    o0.z = pack2(b2.x*inv, b2.y*inv);  o0.w = pack2(b3.x*inv, b3.y*inv);
    o1.x = pack2(b4.x*inv, b4.y*inv);  o1.y = pack2(b5.x*inv, b5.y*inv);
    o1.z = pack2(b6.x*inv, b6.y*inv);  o1.w = pack2(b7.x*inv, b7.y*inv);
    size_t base = (size_t)node*16 + (size_t)sl*2;
    mean4[base]   = o0;
    mean4[base+1] = o1;
  }
}

// ---------------- hidden-layer GEMM (LDS-staged B, round-4 structure), optional fused yl mini-GEMM ----------------

template<bool YL>
__global__ __launch_bounds__(256, 2) void k_gemm_hid(
    const unsigned short* __restrict__ A0, const unsigned short* __restrict__ A1,
    const unsigned short* __restrict__ Bpk, const float* __restrict__ sc,
    const float* __restrict__ sh, const unsigned short* __restrict__ BpkL,
    unsigned short* __restrict__ outh, unsigned* __restrict__ outq,
    unsigned* __restrict__ outyl, int n){
  __shared__ unsigned short Bs[256*128];   // 64 KB
  int t = threadIdx.x;
  {
    const uint4* s = (const uint4*)Bpk;
    uint4* d = (uint4*)Bs;
    #pragma unroll
    for (int i=0;i<16;i++) d[i*256 + t] = s[i*256 + t];
  }
  __syncthreads();

  int lane = t & 63, w = t >> 6;
  int quad = lane >> 4, c = lane & 15;
  int mb = blockIdx.x*128, woff = w*32;
  int r0 = mb + woff + c;
  int r1 = r0 + 16;

  f32x4 acc[2][8];
  #pragma unroll
  for (int mt=0;mt<2;mt++)
    #pragma unroll
    for (int nt=0;nt<8;nt++) acc[mt][nt] = (f32x4){0.f,0.f,0.f,0.f};

  #pragma unroll
  for (int kk=0; kk<8; kk++){
    const unsigned short* ab = (kk >= 4) ? A1 : A0;
    int ka = (kk & 3)*32 + quad*8;
    short8 a0 = {0,0,0,0,0,0,0,0}, a1 = {0,0,0,0,0,0,0,0};
    if (r0 < n) a0 = *(const short8*)(ab + (size_t)r0*128 + ka);
    if (r1 < n) a1 = *(const short8*)(ab + (size_t)r1*128 + ka);
    #pragma unroll
    for (int nt=0; nt<8; nt++){
      short8 b = *(const short8*)&Bs[(size_t)((kk*8 + nt)*64 + lane)*8];
      acc[0][nt] = __builtin_amdgcn_mfma_f32_16x16x32_bf16(a0, b, acc[0][nt], 0, 0, 0);
      acc[1][nt] = __builtin_amdgcn_mfma_f32_16x16x32_bf16(a1, b, acc[1][nt], 0, 0, 0);
    }
  }

  float scv[8], shv[8];
  #pragma unroll
  for (int nt=0;nt<8;nt++){ scv[nt] = sc[nt*16 + c]; shv[nt] = sh[nt*16 + c]; }

  #pragma unroll
  for (int mt=0; mt<2; mt++){
    #pragma unroll
    for (int r=0;r<4;r++){
      int row = mb + woff + mt*16 + quad*4 + r;
      if (row < n){
        float u[8];
        #pragma unroll
        for (int nt=0;nt<8;nt++){
          float uu = acc[mt][nt][r]*scv[nt] + shv[nt];
          u[nt] = fmaxf(uu, 0.f);
          outh[(size_t)row*128 + nt*16 + c] = f2bf(u[nt]);
        }
        if constexpr (!YL){
          // fp8(perm) copy for the next layer's gather: bytes row*128 + c*8 + j hold channel j*16+c
          uint2 q;
          q.x = pk_fp8x4(u[0], u[1], u[2], u[3]);
          q.y = pk_fp8x4(u[4], u[5], u[6], u[7]);
          ((uint2*)outq)[(size_t)row*16 + c] = q;
        }
      }
    }
  }

  if constexpr (YL){
    __syncthreads();   // everyone done reading Bs; outh tile visible block-wide after barrier
    {
      // restage own h tile (128 rows x 128 bf16 = 2048 uint4) into Bs[0..16384)
      uint4* d = (uint4*)Bs;
      const uint4* s4 = (const uint4*)outh;
      #pragma unroll
      for (int i=0;i<8;i++){
        int idx = i*256 + t;
        int row = idx >> 4;
        int gr = mb + row; if (gr > n-1) gr = n-1;
        d[idx] = s4[(size_t)gr*16 + (idx & 15)];
      }
      // stage BpkL (128x64 = 1024 uint4) at short-offset 16384
      const uint4* sL = (const uint4*)BpkL;
      #pragma unroll
      for (int i=0;i<4;i++) d[2048 + i*256 + t] = sL[i*256 + t];
    }
    __syncthreads();
    f32x4 acc2[2][4];
    #pragma unroll
    for (int mt=0;mt<2;mt++)
      #pragma unroll
      for (int nt=0;nt<4;nt++) acc2[mt][nt] = (f32x4){0.f,0.f,0.f,0.f};
    int r0l = woff + c, r1l = r0l + 16;
    #pragma unroll
    for (int kk=0; kk<4; kk++){
      int ka = kk*32 + quad*8;
      short8 a0 = *(const short8*)&Bs[(size_t)r0l*128 + ka];
      short8 a1 = *(const short8*)&Bs[(size_t)r1l*128 + ka];
      #pragma unroll
      for (int nt=0; nt<4; nt++){
        short8 b = *(const short8*)&Bs[16384 + (size_t)((kk*4 + nt)*64 + lane)*8];
        acc2[0][nt] = __builtin_amdgcn_mfma_f32_16x16x32_bf16(a0, b, acc2[0][nt], 0, 0, 0);
        acc2[1][nt] = __builtin_amdgcn_mfma_f32_16x16x32_bf16(a1, b, acc2[1][nt], 0, 0, 0);
      }
    }
    #pragma unroll
    for (int mt=0; mt<2; mt++){
      #pragma unroll
      for (int r=0;r<4;r++){
        int row = mb + woff + mt*16 + quad*4 + r;
        if (row < n){
          // fp8(perm2): byte row*64 + c*4 + nt holds channel nt*16+c
          unsigned q = pk_fp8x4(acc2[0][0][r], acc2[0][1][r], acc2[0][2][r], acc2[0][3][r]);
          unsigned q1 = pk_fp8x4(acc2[1][0][r], acc2[1][1][r], acc2[1][2][r], acc2[1][3][r]);
          outyl[(size_t)row*16 + c] = (mt == 0) ? q : q1;
        }
      }
    }
  }
}

// ---------------- fused layer-3: mean-yl gather (64-dim fp8, rank slots) + GEMM (h_b@Wr2^T) + BN + L2norm ----------------

__global__ __launch_bounds__(256, 2) void k_aggf(
    const uint4* __restrict__ ylq4, const int* __restrict__ offR, const int* __restrict__ csr,
    const int* __restrict__ nodemap,
    const unsigned short* __restrict__ A0, const unsigned short* __restrict__ BpkR,
    const float* __restrict__ sc, const float* __restrict__ sh,
    float* __restrict__ outf, int n){
  __shared__ unsigned short Ms[128*64];   // 16 KB mean-yl tile (bf16, perm2 positions)
  __shared__ unsigned short Bs[128*64];   // 16 KB BpkR
  __shared__ int scsr[AGGF_CAP];          // 12 KB staged csr window
  __shared__ int sw[2];
  int t = threadIdx.x;
  int mb = blockIdx.x*128;
  if (t < 2) sw[t] = offR[min(mb + t*128, n)];
  {
    const uint4* s = (const uint4*)BpkR;
    uint4* d = (uint4*)Bs;
    #pragma unroll
    for (int i=0;i<4;i++) d[i*256 + t] = s[i*256 + t];
  }
  __syncthreads();
  int e0b = sw[0];
  int span = sw[1] - e0b;
  for (int i = t; i < span && i < AGGF_CAP; i += 256) scsr[i] = csr[e0b + i];
  __syncthreads();

  int lane = t & 63, w = t >> 6;
  int sl4 = lane & 3;

  // gather phase: rank slots; wave w covers ranks [w*32, w*32+32), 16 at a time, 4 lanes x uint4 each
  #pragma unroll
  for (int it=0; it<2; it++){
    int rk = w*32 + it*16 + (lane >> 2);
    int idx = mb + rk;
    bool valid = idx < n;
    int s0 = valid ? offR[idx]   : 0;
    int s1 = valid ? offR[idx+1] : 0;
    int ln = valid ? (nodemap[idx] - mb) : rk;
    f32x2 b0={0,0},b1={0,0},b2={0,0},b3={0,0},b4={0,0},b5={0,0},b6={0,0},b7={0,0};
    int e = s0;
    for (; e + 8 <= s1; e += 8){
      int le = e - e0b;
      int i0,i1,i2,i3,i4,i5,i6,i7;
      if (le + 8 <= AGGF_CAP){
        i0 = scsr[le];   i1 = scsr[le+1]; i2 = scsr[le+2]; i3 = scsr[le+3];
        i4 = scsr[le+4]; i5 = scsr[le+5]; i6 = scsr[le+6]; i7 = scsr[le+7];
      } else {
        i0 = csr[e];   i1 = csr[e+1]; i2 = csr[e+2]; i3 = csr[e+3];
        i4 = csr[e+4]; i5 = csr[e+5]; i6 = csr[e+6]; i7 = csr[e+7];
      }
      uint4 v0 = ylq4[(size_t)i0*4 + sl4];
      uint4 v1 = ylq4[(size_t)i1*4 + sl4];
      uint4 v2 = ylq4[(size_t)i2*4 + sl4];
      uint4 v3 = ylq4[(size_t)i3*4 + sl4];
      uint4 v4 = ylq4[(size_t)i4*4 + sl4];
      uint4 v5 = ylq4[(size_t)i5*4 + sl4];
      uint4 v6 = ylq4[(size_t)i6*4 + sl4];
      uint4 v7 = ylq4[(size_t)i7*4 + sl4];
      ACCP16(v0); ACCP16(v1); ACCP16(v2); ACCP16(v3);
      ACCP16(v4); ACCP16(v5); ACCP16(v6); ACCP16(v7);
    }
    for (; e + 4 <= s1; e += 4){
      int le = e - e0b;
      int i0,i1,i2,i3;
      if (le + 4 <= AGGF_CAP){
        i0 = scsr[le]; i1 = scsr[le+1]; i2 = scsr[le+2]; i3 = scsr[le+3];
      } else {
        i0 = csr[e]; i1 = csr[e+1]; i2 = csr[e+2]; i3 = csr[e+3];
      }
      uint4 v0 = ylq4[(size_t)i0*4 + sl4];
      uint4 v1 = ylq4[(size_t)i1*4 + sl4];
      uint4 v2 = ylq4[(size_t)i2*4 + sl4];
      uint4 v3 = ylq4[(size_t)i3*4 + sl4];
      ACCP16(v0); ACCP16(v1); ACCP16(v2); ACCP16(v3);
    }
    for (; e < s1; e++){
      int le = e - e0b;
      int ii = (le < AGGF_CAP) ? scsr[le] : csr[e];
      uint4 v = ylq4[(size_t)ii*4 + sl4];
      ACCP16(v);
    }
    int d = s1 - s0;
    float inv = 1.0f / (float)(d > 0 ? d : 1);
    uint4 o0, o1;
    o0.x = pack2(b0.x*inv, b0.y*inv);  o0.y = pack2(b1.x*inv, b1.y*inv);
    o0.z = pack2(b2.x*inv, b2.y*inv);  o0.w = pack2(b3.x*inv, b3.y*inv);
    o1.x = pack2(b4.x*inv, b4.y*inv);  o1.y = pack2(b5.x*inv, b5.y*inv);
    o1.z = pack2(b6.x*inv, b6.y*inv);  o1.w = pack2(b7.x*inv, b7.y*inv);
    ((uint4*)Ms)[ln*8 + sl4*2]     = o0;
    ((uint4*)Ms)[ln*8 + sl4*2 + 1] = o1;
  }
  __syncthreads();

  // GEMM phase: C = h_b @ Wr2^T (K=128), + mean-yl, BN, L2-normalize
  int quad = lane >> 4, c = lane & 15;
  int woff = w*32;
  int r0 = mb + woff + c;
  int r1 = r0 + 16;
  f32x4 acc[2][4];
  #pragma unroll
  for (int mt=0;mt<2;mt++)
    #pragma unroll
    for (int nt=0;nt<4;nt++) acc[mt][nt] = (f32x4){0.f,0.f,0.f,0.f};
  #pragma unroll
  for (int kk=0; kk<4; kk++){
    int ka = kk*32 + quad*8;
    short8 a0 = {0,0,0,0,0,0,0,0}, a1 = {0,0,0,0,0,0,0,0};
    if (r0 < n) a0 = *(const short8*)(A0 + (size_t)r0*128 + ka);
    if (r1 < n) a1 = *(const short8*)(A0 + (size_t)r1*128 + ka);
    #pragma unroll
    for (int nt=0; nt<4; nt++){
      short8 b = *(const short8*)&Bs[(size_t)((kk*4 + nt)*64 + lane)*8];
      acc[0][nt] = __builtin_amdgcn_mfma_f32_16x16x32_bf16(a0, b, acc[0][nt], 0, 0, 0);
      acc[1][nt] = __builtin_amdgcn_mfma_f32_16x16x32_bf16(a1, b, acc[1][nt], 0, 0, 0);
    }
  }

  float scv[4], shv[4];
  #pragma unroll
  for (int nt=0;nt<4;nt++){ scv[nt] = sc[nt*16 + c]; shv[nt] = sh[nt*16 + c]; }

  #pragma unroll
  for (int mt=0; mt<2; mt++){
    #pragma unroll
    for (int r=0;r<4;r++){
      int lr = woff + mt*16 + quad*4 + r;
      int row = mb + lr;
      float v[4];
      float ss = 0.f;
      if (row < n){
        #pragma unroll
        for (int nt=0;nt<4;nt++){
          // Ms holds perm2 positions: channel nt*16+c lives at position c*4+nt
          float u = acc[mt][nt][r] + bf2f(Ms[lr*64 + c*4 + nt]);
          u = u*scv[nt] + shv[nt];
          v[nt] = u;
          ss += u*u;
        }
      } else {
        #pragma unroll
        for (int nt=0;nt<4;nt++) v[nt] = 0.f;
      }
      ss += __shfl_xor(ss, 1, 64);
      ss += __shfl_xor(ss, 2, 64);
      ss += __shfl_xor(ss, 4, 64);
      ss += __shfl_xor(ss, 8, 64);
      float rn = 1.0f / fmaxf(sqrtf(ss), 1e-12f);
      if (row < n){
        #pragma unroll
        for (int nt=0;nt<4;nt++) outf[(size_t)row*64 + nt*16 + c] = v[nt]*rn;
      }
    }
  }
}

// ---------------- launcher ----------------

extern "C" void kernel_launch(void* const* d_in, const int* in_sizes, int n_in,
                              void* d_out, int out_size, void* d_ws, size_t ws_size,
                              hipStream_t stream){
  const float* x = (const float*)d_in[0];
  const int* ei  = (const int*)d_in[1];
  int N = in_sizes[0] / 128;
  int E = in_sizes[1] / 2;
  const int* esrc = ei;
  const int* edst = ei + E;
  int nbuck = CDIV(N, 128);

  const float *Wl[3], *bl[3], *Wr[3], *g[3], *bb[3], *rm[3], *rv[3];
  int dout[3];
  for (int i=0;i<3;i++){
    int base = 2 + 7*i;
    Wl[i]=(const float*)d_in[base];   bl[i]=(const float*)d_in[base+1];
    Wr[i]=(const float*)d_in[base+2]; g[i] =(const float*)d_in[base+3];
    bb[i]=(const float*)d_in[base+4]; rm[i]=(const float*)d_in[base+5];
    rv[i]=(const float*)d_in[base+6];
    dout[i] = in_sizes[base] / 128;
  }

  char* p = (char*)d_ws;
  size_t o = 0;
  auto alloc = [&](size_t bytes)->void*{ void* r = p + o; o += (bytes + 255) & ~(size_t)255; return r; };
  int* bz    = (int*)alloc((size_t)2*nbuck*4);   // bcnt | bcur (one memset)
  int* bcnt  = bz;
  int* bcur  = bz + nbuck;
  int* offR  = (int*)alloc((size_t)(N+1)*4);     // rank-indexed csr offsets
  int* nodemap = (int*)alloc((size_t)N*4);       // rank slot -> node id
  int* csr   = (int*)alloc((size_t)E*4);
  unsigned* ebuf = (unsigned*)alloc((size_t)E*4);
  unsigned* xb   = (unsigned*)alloc((size_t)N*64*4);   // bf16 x (natural)
  unsigned* xq   = (unsigned*)alloc((size_t)N*128);    // fp8 x (identity order)
  unsigned* mb   = (unsigned*)alloc((size_t)N*64*4);   // bf16 mean (position pass-through)
  unsigned* h_a  = (unsigned*)alloc((size_t)N*64*4);   // bf16 h1 (natural)
  unsigned* haq  = (unsigned*)alloc((size_t)N*128);    // fp8 h1 (perm)
  unsigned* h_b  = (unsigned*)alloc((size_t)N*64*4);   // bf16 h2 (natural)
  unsigned* ylb  = (unsigned*)alloc((size_t)N*64);     // fp8 yl (perm2)
  unsigned short* Bpk01[2];
  float* sc[3]; float* sh[3];
  for (int i=0;i<2;i++) Bpk01[i] = (unsigned short*)alloc((size_t)256*dout[i]*2);
  unsigned short* BpkL = (unsigned short*)alloc((size_t)128*dout[2]*2);
  unsigned short* BpkR = (unsigned short*)alloc((size_t)128*dout[2]*2);
  for (int i=0;i<3;i++){
    sc[i] = (float*)alloc((size_t)dout[i]*4);
    sh[i] = (float*)alloc((size_t)dout[i]*4);
  }

  hipMemsetAsync(bz, 0, (size_t)2*nbuck*4, stream);

  WtpArgs wa[4];
  wa[0] = { Wl[0], Wr[0], bl[0], g[0], bb[0], rm[0], rv[0], Bpk01[0], sc[0], sh[0], 8, dout[0], 1, CDIV(256*dout[0]+dout[0],256), 0 };
  wa[1] = { Wl[1], Wr[1], bl[1], g[1], bb[1], rm[1], rv[1], Bpk01[1], sc[1], sh[1], 8, dout[1], 1, CDIV(256*dout[1]+dout[1],256), 1 };
  wa[2] = { Wl[2], nullptr, nullptr, nullptr, nullptr, nullptr, nullptr, BpkL, nullptr, nullptr, 4, dout[2], 0, CDIV(128*dout[2],256), 0 };
  wa[3] = { Wr[2], nullptr, bl[2], g[2], bb[2], rm[2], rv[2], BpkR, sc[2], sh[2], 4, dout[2], 1, CDIV(128*dout[2]+dout[2],256), 0 };

  int castBlocks = CDIV(N*32, 256);
  int histBlocks = CDIV(E, 256*16);
  int prepBlocks = castBlocks + histBlocks + wa[0].nblk + wa[1].nblk + wa[2].nblk + wa[3].nblk;
  k_prep   <<<prepBlocks,256,0,stream>>>(x, N*32, xb, xq, edst, E, bcnt, nbuck, castBlocks, histBlocks,
                                         wa[0], wa[1], wa[2], wa[3]);
  k_bucketA<<<CDIV(E,256*16),256,0,stream>>>(esrc, edst, E, bcnt, bcur, ebuf, nbuck);
  k_bucketB<<<nbuck,256,0,stream>>>(ebuf, bcnt, nbuck, E, N, offR, csr, nodemap);

  // layer 0
  k_agg<<<CDIV(N,32),256,0,stream>>>((const uint4*)xq, offR, csr, nodemap, N, (uint4*)mb);
  k_gemm_hid<false><<<CDIV(N,128),256,0,stream>>>((const unsigned short*)mb, (const unsigned short*)xb,
                                                  Bpk01[0], sc[0], sh[0], nullptr,
                                                  (unsigned short*)h_a, haq, nullptr, N);
  // layer 1 (+ fused yl = h_b @ Wl2^T, emitted as fp8 perm2)
  k_agg<<<CDIV(N,32),256,0,stream>>>((const uint4*)haq, offR, csr, nodemap, N, (uint4*)mb);
  k_gemm_hid<true><<<CDIV(N,128),256,0,stream>>>((const unsigned short*)mb, (const unsigned short*)h_a,
                                                 Bpk01[1], sc[1], sh[1], BpkL,
                                                 (unsigned short*)h_b, nullptr, ylb, N);
  // layer 2: fused mean-yl gather + final GEMM + BN + L2norm
  k_aggf<<<CDIV(N,128),256,0,stream>>>((const uint4*)ylb, offR, csr, nodemap,
                                       (const unsigned short*)h_b, BpkR, sc[2], sh[2],
                                       (float*)d_out, N);
}